// Round 8
// baseline (2573.077 us; speedup 1.0000x reference)
//
// CaptionDecoder on MI355X — round 8: fence-free coherent messaging.
// R7 lesson: agent acquire fences nuke L1/L2 each barrier -> every phase runs
// at L3 latency. Fix: no fences; cross-block data via per-access coherent
// atomics (L2 stays warm for read-only data); WhT in registers; phase D gate
// dots from LDS-staged x (latency-bound -> BW-bound).
#include <hip/hip_runtime.h>

#define E 512
#define H 512
#define V 32000
#define B 32
#define P 196
#define T 32
#define NB 256
#define NT 512

typedef __attribute__((ext_vector_type(8))) short s8v;    // 8 bf16
typedef __attribute__((ext_vector_type(4))) float f4v;    // 4 f32 acc

__device__ __forceinline__ float bf16_to_f(unsigned short u){
  return __uint_as_float(((unsigned)u) << 16);
}
__device__ __forceinline__ unsigned short f_to_bf16(float f){
  unsigned u = __float_as_uint(f);
  u += 0x7FFFu + ((u >> 16) & 1u);   // RNE
  return (unsigned short)(u >> 16);
}
__device__ __forceinline__ float fast_tanh(float x){
  float e = __expf(2.0f*x);
  return 1.0f - 2.0f/(e + 1.0f);
}
__device__ __forceinline__ float sigmoidf_(float x){
  return 1.0f/(1.0f + __expf(-x));
}
__device__ __forceinline__ void load_lds16(const unsigned short* g, unsigned short* l){
  __builtin_amdgcn_global_load_lds(
      (const __attribute__((address_space(1))) void*)g,
      (__attribute__((address_space(3))) void*)l, 16, 0, 0);
}
__device__ __forceinline__ float dot4(float4 a, float4 b){
  return a.x*b.x + a.y*b.y + a.z*b.z + a.w*b.w;
}

#define AT_SCOPE __HIP_MEMORY_SCOPE_AGENT
// Coherent (cache-bypassing) scalar access for cross-block data. Keeps L1/L2
// warm for everything else because we never issue agent-scope fences.
__device__ __forceinline__ float cohload(const float* p){
  return __hip_atomic_load(p, __ATOMIC_RELAXED, AT_SCOPE);
}
__device__ __forceinline__ void cohstore(float* p, float v){
  __hip_atomic_store(p, v, __ATOMIC_RELAXED, AT_SCOPE);
}

// Flag-array barrier, fence-free. __syncthreads drains each wave's vmem
// (coherent stores included) before the release publish; waiters poll relaxed.
// Subsequent cross-block reads are themselves coherent, so no acquire fence.
__device__ __forceinline__ void bar_flag(unsigned* my, const unsigned* wait_base,
                                         int n, unsigned gen){
  __syncthreads();
  if (threadIdx.x == 0)
    __hip_atomic_store(my, gen, __ATOMIC_RELEASE, AT_SCOPE);
  if (threadIdx.x < 64){
    for (;;){
      unsigned mn = 0xffffffffu;
      for (int i = (int)threadIdx.x; i < n; i += 64){
        unsigned v = __hip_atomic_load(wait_base + i, __ATOMIC_RELAXED, AT_SCOPE);
        mn = v < mn ? v : mn;
      }
      #pragma unroll
      for (int off = 32; off; off >>= 1){
        unsigned o2 = (unsigned)__shfl_xor((int)mn, off);
        mn = o2 < mn ? o2 : mn;
      }
      if (mn >= gen) break;
      __builtin_amdgcn_s_sleep(1);
    }
    __builtin_amdgcn_sched_barrier(0);
  }
  __syncthreads();
}

// ---------------------------------------------------------------------------
// f32 (strided) -> bf16 hi (+ optional lo residual). cols==512.
__global__ void split_kernel(const float* __restrict__ src, int src_ld, int src_coff,
                             int rows,
                             unsigned short* __restrict__ dhi, unsigned short* __restrict__ dlo,
                             int dst_ld, int dst_coff)
{
  int n = rows << 9;
  for (int i = blockIdx.x*blockDim.x + threadIdx.x; i < n; i += gridDim.x*blockDim.x){
    int r = i >> 9, c = i & 511;
    float x = src[(size_t)r*src_ld + src_coff + c];
    unsigned short h = f_to_bf16(x);
    dhi[(size_t)r*dst_ld + dst_coff + c] = h;
    if (dlo) dlo[(size_t)r*dst_ld + dst_coff + c] = f_to_bf16(x - bf16_to_f(h));
  }
}

// Embedding gather -> f32, row = b*T+t
__global__ void embed_kernel(const int* __restrict__ caps, const float* __restrict__ embW,
                             float* __restrict__ emb)
{
  int row = blockIdx.x;
  int cap = caps[row];
  const float4* s = (const float4*)(embW + (size_t)cap*E);
  float4* d = (float4*)(emb + (size_t)row*E);
  for (int e = threadIdx.x; e < E/4; e += blockDim.x) d[e] = s[e];
}

// mean over P, then h0/c0 = mean@W^T + b
__global__ __launch_bounds__(512) void prep_kernel(
    const float* __restrict__ feats,
    const float* __restrict__ inith_W, const float* __restrict__ inith_b,
    const float* __restrict__ initc_W, const float* __restrict__ initc_b,
    float* __restrict__ h_state, float* __restrict__ c_state)
{
  __shared__ float mf[E];
  const int b = blockIdx.x, tid = threadIdx.x;
  const float* fb = feats + (size_t)b*P*E + tid;
  float s = 0.f;
  for (int p = 0; p < P; ++p) s += fb[(size_t)p*E];
  mf[tid] = s * (1.0f/196.0f);
  __syncthreads();
  const float* wh = inith_W + (size_t)tid*E;
  const float* wc = initc_W + (size_t)tid*E;
  float h0 = inith_b[tid], c0 = initc_b[tid];
  #pragma unroll 4
  for (int e = 0; e < E; e += 4){
    float4 a4 = *(const float4*)(wh + e);
    float4 b4 = *(const float4*)(wc + e);
    float4 m4 = *(const float4*)(mf + e);
    h0 += dot4(a4, m4);
    c0 += dot4(b4, m4);
  }
  h_state[b*H + tid] = h0;
  c_state[b*H + tid] = c0;
}

// WhT[k][j] = attn_W[j][E + k]  (64x64 LDS tiles, coalesced both sides)
__global__ __launch_bounds__(256) void transpose_wh_kernel(
    const float* __restrict__ attn_W, float* __restrict__ WhT)
{
  __shared__ float tile[64][65];
  const int jt = blockIdx.x & 7, kt = blockIdx.x >> 3;
  const int tx = threadIdx.x & 63, ty = threadIdx.x >> 6;
  for (int r = ty; r < 64; r += 4)
    tile[r][tx] = attn_W[(size_t)(jt*64 + r)*(E+H) + E + kt*64 + tx];
  __syncthreads();
  for (int r = ty; r < 64; r += 4)
    WhT[(size_t)(kt*64 + r)*512 + jt*64 + tx] = tile[tx][r];
}

// ---------------------------------------------------------------------------
// m97-style bf16 GEMM: C = sum_passes A_p (MxK) * B_p(NxK)^T [+bias]
__global__ __launch_bounds__(256) void gemm_bt_kernel(
    const unsigned short* __restrict__ A0, const unsigned short* __restrict__ A1,
    const unsigned short* __restrict__ A2,
    const unsigned short* __restrict__ B0, const unsigned short* __restrict__ B1,
    const unsigned short* __restrict__ B2,
    float* __restrict__ Cc, const float* __restrict__ bias,
    int N, int K, int npasses, int mt, int swz)
{
  __shared__ __align__(16) unsigned short Al[128*32];
  __shared__ __align__(16) unsigned short Bl[128*32];
  const int tid = threadIdx.x;
  const int wid = tid >> 6, l = tid & 63;
  int f = blockIdx.x;
  if (swz) f = (f & 7)*((int)gridDim.x >> 3) + (f >> 3);
  const int m0 = (f % mt)*128, n0 = (f / mt)*128;
  const int wr = wid >> 1, wc = wid & 1;

  f4v acc[4][4];
  #pragma unroll
  for (int i = 0; i < 4; ++i)
    #pragma unroll
    for (int j = 0; j < 4; ++j) acc[i][j] = (f4v){0.f,0.f,0.f,0.f};

  const int s0 = tid, s1 = tid + 256;
  const int r0 = s0 >> 2, g0 = (s0 & 3) ^ ((r0 >> 1) & 3);
  const int r1 = s1 >> 2, g1 = (s1 & 3) ^ ((r1 >> 1) & 3);
  const int la = l & 15, ch = l >> 4;

  for (int pass = 0; pass < npasses; ++pass){
    const unsigned short* Ap = pass == 0 ? A0 : (pass == 1 ? A1 : A2);
    const unsigned short* Bp = pass == 0 ? B0 : (pass == 1 ? B1 : B2);
    for (int k0 = 0; k0 < K; k0 += 32){
      __syncthreads();
      load_lds16(Ap + (size_t)(m0 + r0)*K + k0 + g0*8, Al + s0*8);
      load_lds16(Ap + (size_t)(m0 + r1)*K + k0 + g1*8, Al + s1*8);
      load_lds16(Bp + (size_t)(n0 + r0)*K + k0 + g0*8, Bl + s0*8);
      load_lds16(Bp + (size_t)(n0 + r1)*K + k0 + g1*8, Bl + s1*8);
      __syncthreads();
      s8v av[4], bv[4];
      #pragma unroll
      for (int mi = 0; mi < 4; ++mi){
        int row = wr*64 + mi*16 + la;
        int cs = ch ^ ((row >> 1) & 3);
        av[mi] = *(const s8v*)(Al + (row*4 + cs)*8);
      }
      #pragma unroll
      for (int ni = 0; ni < 4; ++ni){
        int row = wc*64 + ni*16 + la;
        int cs = ch ^ ((row >> 1) & 3);
        bv[ni] = *(const s8v*)(Bl + (row*4 + cs)*8);
      }
      #pragma unroll
      for (int mi = 0; mi < 4; ++mi)
        #pragma unroll
        for (int ni = 0; ni < 4; ++ni)
          acc[mi][ni] = __builtin_amdgcn_mfma_f32_16x16x32_bf16(av[mi], bv[ni], acc[mi][ni], 0, 0, 0);
    }
  }
  #pragma unroll
  for (int mi = 0; mi < 4; ++mi){
    int row = m0 + wr*64 + mi*16 + (l >> 4)*4;
    #pragma unroll
    for (int ni = 0; ni < 4; ++ni){
      int col = n0 + wc*64 + ni*16 + (l & 15);
      float bb = bias ? bias[col] : 0.0f;
      #pragma unroll
      for (int r = 0; r < 4; ++r)
        Cc[(size_t)(row + r)*N + col] = acc[mi][ni][r] + bb;
    }
  }
}

// ---------------------------------------------------------------------------
// Persistent loop kernel. blk -> (b = blk&31, sub = blk>>5) for attention;
// blk owns j-pair {2blk, 2blk+1} x 4 gates for LSTM (weights in LDS, x staged
// in LDS per 16-batch half). WhT slice lives in registers. No fences.
__global__ __launch_bounds__(512, 1) void loop_kernel(
    const float* __restrict__ feats, const float* __restrict__ feat_proj,
    const float* __restrict__ WhT, const float* __restrict__ attn_b,
    const float* __restrict__ v_w, const float* __restrict__ emb,
    const float* __restrict__ W_ih, const float* __restrict__ W_hh,
    const float* __restrict__ b_ih, const float* __restrict__ b_hh,
    float* __restrict__ hbuf0, float* __restrict__ hbuf1,
    const float* __restrict__ c_init,
    float* __restrict__ ctx_g, float* __restrict__ s_part,
    unsigned short* __restrict__ hall_h, unsigned short* __restrict__ hall_l,
    unsigned* __restrict__ fm, unsigned* __restrict__ fg1, unsigned* __restrict__ fg2)
{
  __shared__ float Wl[8][1540];    // 49.3KB gate weights [Wih(1024)|Whh(512)]
  __shared__ float xs[16][1540];   // 98.6KB staged x [emb|ctx|h] for 16 batches
  __shared__ float hs[512];
  __shared__ float hwl[64];
  __shared__ float partA[8][72];
  __shared__ float scr[256];
  __shared__ float aux[256];
  __shared__ float bias8[8];
  __shared__ float smx, sinv;

  const int blk = blockIdx.x, tid = threadIdx.x;
  const int b = blk & 31, sub = blk >> 5;
  const int jb = blk*2;
  const int l = tid & 63, wv = tid >> 6;

  // ---- prologue: gate weights -> LDS, WhT slice -> registers ----
  #pragma unroll
  for (int r = 0; r < 8; ++r){
    const int col = (r >> 1)*512 + jb + (r & 1);
    const float4* wi = (const float4*)(W_ih + (size_t)col*1024);
    const float4* wh = (const float4*)(W_hh + (size_t)col*512);
    float4* d0 = (float4*)&Wl[r][0];
    float4* d1 = (float4*)&Wl[r][1024];
    for (int q = tid; q < 256; q += NT) d0[q] = wi[q];
    for (int q = tid; q < 128; q += NT) d1[q] = wh[q];
  }
  float wreg[64];
  #pragma unroll
  for (int kk = 0; kk < 64; ++kk)
    wreg[kk] = WhT[(size_t)(wv*64 + kk)*512 + sub*64 + l];
  if (tid < 8){
    const int col = (tid >> 1)*512 + jb + (tid & 1);
    bias8[tid] = b_ih[col] + b_hh[col];
  }
  const float vl = v_w[sub*64 + l];
  const float ab = (tid < 64) ? attn_b[sub*64 + tid] : 0.f;
  float cA = 0.f, cB = 0.f;      // c-state for (bb=tid>>1, jj=tid&1), halves 0/1
  if (tid < 32){
    cA = c_init[(tid >> 1)*512 + jb + (tid & 1)];
    cB = c_init[(16 + (tid >> 1))*512 + jb + (tid & 1)];
  }
  __syncthreads();

  for (int t = 0; t < T; ++t){
    const float* h_in  = (t & 1) ? hbuf1 : hbuf0;
    float*       h_out = (t & 1) ? hbuf0 : hbuf1;
    const unsigned gen = (unsigned)(t + 1);

    // ---- A: hWh[b][sub*64..+64) from register weights + LDS-broadcast h ----
    hs[tid] = cohload(h_in + b*512 + tid);
    __syncthreads();
    {
      const float* hk = hs + wv*64;
      float a = 0.f;
      #pragma unroll
      for (int kk = 0; kk < 64; ++kk) a += hk[kk] * wreg[kk];
      partA[wv][l] = a;
    }
    __syncthreads();
    if (tid < 64){
      float s = ab;
      #pragma unroll
      for (int k = 0; k < 8; ++k) s += partA[k][tid];
      hwl[tid] = s;
    }
    __syncthreads();

    // ---- B: partial scores over own j-slice (feat_proj from warm L2) ----
    {
      const float hj = hwl[l];
      for (int p = wv; p < P; p += 8){
        float fp = feat_proj[((size_t)b*P + p)*512 + sub*64 + l];
        float e2 = vl * fast_tanh(fp + hj);
        #pragma unroll
        for (int off = 32; off; off >>= 1) e2 += __shfl_xor(e2, off);
        if (l == 0) cohstore(s_part + ((size_t)b*P + p)*8 + sub, e2);
      }
    }
    bar_flag(fm + b*8 + sub, fm + b*8, 8, gen);

    // ---- C: reduce partials -> softmax -> ctx slice (feats from warm L2) ----
    {
      float sc_v = -1e30f;
      if (tid < P){
        const float* sp = s_part + ((size_t)b*P + tid)*8;
        float s8 = 0.f;
        #pragma unroll
        for (int k = 0; k < 8; ++k) s8 += cohload(sp + k);
        sc_v = s8;
      }
      if (tid < 256) aux[tid] = sc_v;
      __syncthreads();
      if (tid < 64){
        float m = -1e30f;
        #pragma unroll
        for (int i = 0; i < 4; ++i) m = fmaxf(m, aux[tid + i*64]);
        #pragma unroll
        for (int off = 32; off; off >>= 1) m = fmaxf(m, __shfl_xor(m, off));
        if (tid == 0) smx = m;
      }
      __syncthreads();
      float al = (tid < P) ? __expf(sc_v - smx) : 0.f;
      if (tid < 256) aux[tid] = al;
      __syncthreads();
      if (tid < 64){
        float s = 0.f;
        #pragma unroll
        for (int i = 0; i < 4; ++i) s += aux[tid + i*64];
        #pragma unroll
        for (int off = 32; off; off >>= 1) s += __shfl_xor(s, off);
        if (tid == 0) sinv = 1.0f/s;
      }
      __syncthreads();
      float a = 0.f;
      for (int p = wv; p < P; p += 8)
        a += aux[p] * feats[((size_t)b*P + p)*512 + sub*64 + l];
      partA[wv][l] = a;
      __syncthreads();
      if (tid < 64){
        float s = 0.f;
        #pragma unroll
        for (int k = 0; k < 8; ++k) s += partA[k][tid];
        cohstore(ctx_g + b*512 + sub*64 + tid, s * sinv);
      }
    }
    bar_flag(fg1 + blk, fg1, NB, gen);

    // ---- D: two 16-batch halves; stage x to LDS, dot from LDS ----
    #pragma unroll
    for (int half = 0; half < 2; ++half){
      const int b0 = half*16;
      // stage: emb plain f4 (L2-warm), ctx/h coherent scalars
      for (int q = tid; q < 2048; q += NT){
        const int bb = q >> 7, i = (q & 127)*4;
        *(float4*)&xs[bb][i] = *(const float4*)&emb[((size_t)(b0 + bb)*T + t)*512 + i];
      }
      for (int q = tid; q < 8192; q += NT){
        const int bb = q >> 9, i = q & 511;
        xs[bb][512 + i] = cohload(ctx_g + (b0 + bb)*512 + i);
      }
      for (int q = tid; q < 8192; q += NT){
        const int bb = q >> 9, i = q & 511;
        xs[bb][1024 + i] = cohload(h_in + (b0 + bb)*512 + i);
      }
      __syncthreads();
      // dots: tid<256: kh = tid>>7 (K half), o = tid&127: bb=o>>3, c=o&7
      if (tid < 256){
        const int kh = tid >> 7, o = tid & 127, bb = o >> 3, c = o & 7;
        const float4* xr = (const float4*)&xs[bb][kh*768];
        const float4* wr = (const float4*)&Wl[c][kh*768];
        float a0 = 0.f, a1 = 0.f;
        #pragma unroll 16
        for (int i = 0; i < 192; i += 2){
          a0 += dot4(wr[i], xr[i]);
          a1 += dot4(wr[i+1], xr[i+1]);
        }
        scr[tid] = a0 + a1;
      }
      __syncthreads();
      if (tid < 32){
        const int bb = tid >> 1, jj = tid & 1;
        float gv[4];
        #pragma unroll
        for (int g = 0; g < 4; ++g){
          const int c = g*2 + jj, o = bb*8 + c;
          gv[g] = scr[o] + scr[128 + o] + bias8[c];
        }
        const float i_ = sigmoidf_(gv[0]);
        const float f_ = sigmoidf_(gv[1]);
        const float g_ = fast_tanh(gv[2]);
        const float o_ = sigmoidf_(gv[3]);
        const int gb = b0 + bb, j = jb + jj;
        const float c_old = half ? cB : cA;
        const float c_new = f_*c_old + i_*g_;
        const float h_new = o_*fast_tanh(c_new);
        if (half) cB = c_new; else cA = c_new;
        cohstore(h_out + gb*512 + j, h_new);
        const unsigned short hh = f_to_bf16(h_new);
        hall_h[((size_t)gb*T + t)*512 + j] = hh;
        hall_l[((size_t)gb*T + t)*512 + j] = f_to_bf16(h_new - bf16_to_f(hh));
      }
      __syncthreads();
    }
    bar_flag(fg2 + blk, fg2, NB, gen);
  }
}

// ---------------------------------------------------------------------------
extern "C" void kernel_launch(void* const* d_in, const int* in_sizes, int n_in,
                              void* d_out, int out_size, void* d_ws, size_t ws_size,
                              hipStream_t stream)
{
  (void)in_sizes; (void)n_in; (void)out_size;
  const float* features = (const float*)d_in[0];
  const int*   captions = (const int*)d_in[1];
  const float* embed_W  = (const float*)d_in[2];
  const float* attn_W   = (const float*)d_in[3];
  const float* attn_b   = (const float*)d_in[4];
  const float* v_w      = (const float*)d_in[5];
  const float* W_ih     = (const float*)d_in[6];
  const float* W_hh     = (const float*)d_in[7];
  const float* b_ih     = (const float*)d_in[8];
  const float* b_hh     = (const float*)d_in[9];
  const float* lin_W    = (const float*)d_in[10];
  const float* lin_b    = (const float*)d_in[11];
  const float* inith_W  = (const float*)d_in[12];
  const float* inith_b  = (const float*)d_in[13];
  const float* initc_W  = (const float*)d_in[14];
  const float* initc_b  = (const float*)d_in[15];

  // "early" scratch in d_out (dead before final logits GEMM writes d_out)
  char* o = (char*)d_out;
  unsigned short* feat_bf   = (unsigned short*)o; o += (size_t)(B*P)*E*2;   // 6.4MB
  unsigned short* Wf_bf     = (unsigned short*)o; o += (size_t)H*E*2;       // 0.5MB
  float*          feat_proj = (float*)o;          o += (size_t)(B*P)*H*4;   // 12.9MB

  // persistent scratch in d_ws
  const size_t SZ_LIN  = (size_t)V*H*2;          // 32.77MB
  const size_t SZ_HALL = (size_t)(B*T)*H*2;      // 1MB
  const size_t SZ_EMB  = (size_t)(B*T)*E*4;      // 2.1MB
  const size_t SZ_ST   = (size_t)B*H*4;          // 64KB
  const size_t SZ_WHT  = (size_t)H*H*4;          // 1MB
  const size_t SZ_SP   = (size_t)B*P*8*4;        // 0.2MB
  const size_t SZ_FLG  = 4096;
  const size_t need_wo = SZ_LIN + 2*SZ_HALL + SZ_EMB + 5*SZ_ST + SZ_WHT + SZ_SP + SZ_FLG;
  const bool three = (ws_size >= need_wo + SZ_LIN);

  char* w = (char*)d_ws;
  unsigned short* lin_hi  = (unsigned short*)w; w += SZ_LIN;
  unsigned short* lin_lo  = (unsigned short*)w; if (three) w += SZ_LIN;
  unsigned short* hall_hi = (unsigned short*)w; w += SZ_HALL;
  unsigned short* hall_lo = (unsigned short*)w; w += SZ_HALL;
  float*          emb_ws  = (float*)w;          w += SZ_EMB;
  float*          hbuf0   = (float*)w;          w += SZ_ST;
  float*          hbuf1   = (float*)w;          w += SZ_ST;
  float*          c_state = (float*)w;          w += SZ_ST;
  float*          ctx_ws  = (float*)w;          w += SZ_ST;
  float*          WhT_ws  = (float*)w;          w += SZ_WHT;
  float*          spart   = (float*)w;          w += SZ_SP;
  unsigned*       flags   = (unsigned*)w;       w += SZ_FLG;
  unsigned* fm  = flags;          // [256] mini-barrier flags [b*8+sub]
  unsigned* fg1 = flags + 256;    // [256] grid barrier 1
  unsigned* fg2 = flags + 512;    // [256] grid barrier 2

  // --- conversions / gathers / init ---
  split_kernel<<<2048, 256, 0, stream>>>(features, E, 0, B*P, feat_bf, nullptr, E, 0);
  split_kernel<<<256, 256, 0, stream>>>(attn_W, E+H, 0, H, Wf_bf, nullptr, E, 0);
  split_kernel<<<2048, 256, 0, stream>>>(lin_W, 512, 0, V, lin_hi, three ? lin_lo : nullptr, 512, 0);
  embed_kernel<<<B*T, 128, 0, stream>>>(captions, embed_W, emb_ws);
  prep_kernel<<<B, 512, 0, stream>>>(features, inith_W, inith_b, initc_W, initc_b,
                                     hbuf0, c_state);
  transpose_wh_kernel<<<64, 256, 0, stream>>>(attn_W, WhT_ws);
  hipMemsetAsync(flags, 0, SZ_FLG, stream);

  // feat_proj = features @ Wf^T (bf16 1-pass; error damped through tanh/softmax)
  gemm_bt_kernel<<<(B*P/128)*(E/128), 256, 0, stream>>>(
      feat_bf, feat_bf, feat_bf, Wf_bf, Wf_bf, Wf_bf,
      feat_proj, nullptr, E, E, 1, B*P/128, 0);

  // --- the whole recurrence in one persistent kernel ---
  loop_kernel<<<NB, NT, 0, stream>>>(
      features, feat_proj, WhT_ws, attn_b, v_w, emb_ws, W_ih, W_hh, b_ih, b_hh,
      hbuf0, hbuf1, c_state, ctx_ws, spart, hall_hi, hall_lo, fm, fg1, fg2);

  // --- logits = h_all @ lin_W^T + lin_b (bf16x3, XCD-swizzled grid) ---
  gemm_bt_kernel<<<(V/128)*(B*T/128), 256, 0, stream>>>(
      hall_hi, hall_lo, hall_hi, lin_hi, lin_hi, three ? lin_lo : lin_hi,
      (float*)d_out, lin_b, V, H, three ? 3 : 2, B*T/128, 1);
}

// Round 9
// 2177.588 us; speedup vs baseline: 1.1816x; 1.1816x over previous
//
// CaptionDecoder on MI355X — round 9: ALL-RELAXED barriers (no release/acquire).
// Theory: agent-scope RELEASE on a multi-XCD chip compiles to L2 writeback
// (+acquire -> invalidate); 1 release/block/barrier = ~20us L2 flush stall and
// cold L2 every phase (matches r3..r8 constant ~20us/barrier regardless of
// arrival mechanics). __syncthreads drains vmcnt(0) (stores COMPLETE at the
// coherence point) before the flag store issues, and all cross-block data
// moves via relaxed agent atomics (proven cross-XCD coherent in r8), so no
// release/acquire is needed at all.
#include <hip/hip_runtime.h>

#define E 512
#define H 512
#define V 32000
#define B 32
#define P 196
#define T 32
#define NB 256
#define NT 512

typedef __attribute__((ext_vector_type(8))) short s8v;    // 8 bf16
typedef __attribute__((ext_vector_type(4))) float f4v;    // 4 f32 acc

__device__ __forceinline__ float bf16_to_f(unsigned short u){
  return __uint_as_float(((unsigned)u) << 16);
}
__device__ __forceinline__ unsigned short f_to_bf16(float f){
  unsigned u = __float_as_uint(f);
  u += 0x7FFFu + ((u >> 16) & 1u);   // RNE
  return (unsigned short)(u >> 16);
}
__device__ __forceinline__ float fast_tanh(float x){
  float e = __expf(2.0f*x);
  return 1.0f - 2.0f/(e + 1.0f);
}
__device__ __forceinline__ float sigmoidf_(float x){
  return 1.0f/(1.0f + __expf(-x));
}
__device__ __forceinline__ void load_lds16(const unsigned short* g, unsigned short* l){
  __builtin_amdgcn_global_load_lds(
      (const __attribute__((address_space(1))) void*)g,
      (__attribute__((address_space(3))) void*)l, 16, 0, 0);
}
__device__ __forceinline__ float dot4(float4 a, float4 b){
  return a.x*b.x + a.y*b.y + a.z*b.z + a.w*b.w;
}

#define AT_SCOPE __HIP_MEMORY_SCOPE_AGENT
// Coherent (cache-bypassing) scalar access for cross-block data. RELAXED only.
__device__ __forceinline__ float cohload(const float* p){
  return __hip_atomic_load(p, __ATOMIC_RELAXED, AT_SCOPE);
}
__device__ __forceinline__ void cohstore(float* p, float v){
  __hip_atomic_store(p, v, __ATOMIC_RELAXED, AT_SCOPE);
}

// Flag-array barrier, fully relaxed. Ordering argument:
//  - __syncthreads() forces every wave's s_waitcnt vmcnt(0): all the block's
//    prior global stores have COMPLETED (ack'd at the coherence point).
//  - then tid0 publishes the flag (relaxed agent atomic store -> coherent).
//  - waiters poll relaxed agent atomic loads (bypass stale caches).
//  - data reads after the barrier are themselves relaxed agent atomics.
// No release/acquire -> no buffer_wbl2/inv -> L1/L2 stay warm across phases.
__device__ __forceinline__ void bar_flag(unsigned* my, const unsigned* wait_base,
                                         int n, unsigned gen){
  __syncthreads();
  if (threadIdx.x == 0)
    __hip_atomic_store(my, gen, __ATOMIC_RELAXED, AT_SCOPE);
  if (threadIdx.x < 64){
    for (;;){
      unsigned mn = 0xffffffffu;
      for (int i = (int)threadIdx.x; i < n; i += 64){
        unsigned v = __hip_atomic_load(wait_base + i, __ATOMIC_RELAXED, AT_SCOPE);
        mn = v < mn ? v : mn;
      }
      #pragma unroll
      for (int off = 32; off; off >>= 1){
        unsigned o2 = (unsigned)__shfl_xor((int)mn, off);
        mn = o2 < mn ? o2 : mn;
      }
      if (mn >= gen) break;
      __builtin_amdgcn_s_sleep(1);
    }
    __builtin_amdgcn_sched_barrier(0);
  }
  __syncthreads();
}

// ---------------------------------------------------------------------------
// f32 (strided) -> bf16 hi (+ optional lo residual). cols==512.
__global__ void split_kernel(const float* __restrict__ src, int src_ld, int src_coff,
                             int rows,
                             unsigned short* __restrict__ dhi, unsigned short* __restrict__ dlo,
                             int dst_ld, int dst_coff)
{
  int n = rows << 9;
  for (int i = blockIdx.x*blockDim.x + threadIdx.x; i < n; i += gridDim.x*blockDim.x){
    int r = i >> 9, c = i & 511;
    float x = src[(size_t)r*src_ld + src_coff + c];
    unsigned short h = f_to_bf16(x);
    dhi[(size_t)r*dst_ld + dst_coff + c] = h;
    if (dlo) dlo[(size_t)r*dst_ld + dst_coff + c] = f_to_bf16(x - bf16_to_f(h));
  }
}

// Embedding gather -> f32, row = b*T+t
__global__ void embed_kernel(const int* __restrict__ caps, const float* __restrict__ embW,
                             float* __restrict__ emb)
{
  int row = blockIdx.x;
  int cap = caps[row];
  const float4* s = (const float4*)(embW + (size_t)cap*E);
  float4* d = (float4*)(emb + (size_t)row*E);
  for (int e = threadIdx.x; e < E/4; e += blockDim.x) d[e] = s[e];
}

// mean over P, then h0/c0 = mean@W^T + b
__global__ __launch_bounds__(512) void prep_kernel(
    const float* __restrict__ feats,
    const float* __restrict__ inith_W, const float* __restrict__ inith_b,
    const float* __restrict__ initc_W, const float* __restrict__ initc_b,
    float* __restrict__ h_state, float* __restrict__ c_state)
{
  __shared__ float mf[E];
  const int b = blockIdx.x, tid = threadIdx.x;
  const float* fb = feats + (size_t)b*P*E + tid;
  float s = 0.f;
  for (int p = 0; p < P; ++p) s += fb[(size_t)p*E];
  mf[tid] = s * (1.0f/196.0f);
  __syncthreads();
  const float* wh = inith_W + (size_t)tid*E;
  const float* wc = initc_W + (size_t)tid*E;
  float h0 = inith_b[tid], c0 = initc_b[tid];
  #pragma unroll 4
  for (int e = 0; e < E; e += 4){
    float4 a4 = *(const float4*)(wh + e);
    float4 b4 = *(const float4*)(wc + e);
    float4 m4 = *(const float4*)(mf + e);
    h0 += dot4(a4, m4);
    c0 += dot4(b4, m4);
  }
  h_state[b*H + tid] = h0;
  c_state[b*H + tid] = c0;
}

// WhT[k][j] = attn_W[j][E + k]  (64x64 LDS tiles, coalesced both sides)
__global__ __launch_bounds__(256) void transpose_wh_kernel(
    const float* __restrict__ attn_W, float* __restrict__ WhT)
{
  __shared__ float tile[64][65];
  const int jt = blockIdx.x & 7, kt = blockIdx.x >> 3;
  const int tx = threadIdx.x & 63, ty = threadIdx.x >> 6;
  for (int r = ty; r < 64; r += 4)
    tile[r][tx] = attn_W[(size_t)(jt*64 + r)*(E+H) + E + kt*64 + tx];
  __syncthreads();
  for (int r = ty; r < 64; r += 4)
    WhT[(size_t)(kt*64 + r)*512 + jt*64 + tx] = tile[tx][r];
}

// ---------------------------------------------------------------------------
// m97-style bf16 GEMM: C = sum_passes A_p (MxK) * B_p(NxK)^T [+bias]
__global__ __launch_bounds__(256) void gemm_bt_kernel(
    const unsigned short* __restrict__ A0, const unsigned short* __restrict__ A1,
    const unsigned short* __restrict__ A2,
    const unsigned short* __restrict__ B0, const unsigned short* __restrict__ B1,
    const unsigned short* __restrict__ B2,
    float* __restrict__ Cc, const float* __restrict__ bias,
    int N, int K, int npasses, int mt, int swz)
{
  __shared__ __align__(16) unsigned short Al[128*32];
  __shared__ __align__(16) unsigned short Bl[128*32];
  const int tid = threadIdx.x;
  const int wid = tid >> 6, l = tid & 63;
  int f = blockIdx.x;
  if (swz) f = (f & 7)*((int)gridDim.x >> 3) + (f >> 3);
  const int m0 = (f % mt)*128, n0 = (f / mt)*128;
  const int wr = wid >> 1, wc = wid & 1;

  f4v acc[4][4];
  #pragma unroll
  for (int i = 0; i < 4; ++i)
    #pragma unroll
    for (int j = 0; j < 4; ++j) acc[i][j] = (f4v){0.f,0.f,0.f,0.f};

  const int s0 = tid, s1 = tid + 256;
  const int r0 = s0 >> 2, g0 = (s0 & 3) ^ ((r0 >> 1) & 3);
  const int r1 = s1 >> 2, g1 = (s1 & 3) ^ ((r1 >> 1) & 3);
  const int la = l & 15, ch = l >> 4;

  for (int pass = 0; pass < npasses; ++pass){
    const unsigned short* Ap = pass == 0 ? A0 : (pass == 1 ? A1 : A2);
    const unsigned short* Bp = pass == 0 ? B0 : (pass == 1 ? B1 : B2);
    for (int k0 = 0; k0 < K; k0 += 32){
      __syncthreads();
      load_lds16(Ap + (size_t)(m0 + r0)*K + k0 + g0*8, Al + s0*8);
      load_lds16(Ap + (size_t)(m0 + r1)*K + k0 + g1*8, Al + s1*8);
      load_lds16(Bp + (size_t)(n0 + r0)*K + k0 + g0*8, Bl + s0*8);
      load_lds16(Bp + (size_t)(n0 + r1)*K + k0 + g1*8, Bl + s1*8);
      __syncthreads();
      s8v av[4], bv[4];
      #pragma unroll
      for (int mi = 0; mi < 4; ++mi){
        int row = wr*64 + mi*16 + la;
        int cs = ch ^ ((row >> 1) & 3);
        av[mi] = *(const s8v*)(Al + (row*4 + cs)*8);
      }
      #pragma unroll
      for (int ni = 0; ni < 4; ++ni){
        int row = wc*64 + ni*16 + la;
        int cs = ch ^ ((row >> 1) & 3);
        bv[ni] = *(const s8v*)(Bl + (row*4 + cs)*8);
      }
      #pragma unroll
      for (int mi = 0; mi < 4; ++mi)
        #pragma unroll
        for (int ni = 0; ni < 4; ++ni)
          acc[mi][ni] = __builtin_amdgcn_mfma_f32_16x16x32_bf16(av[mi], bv[ni], acc[mi][ni], 0, 0, 0);
    }
  }
  #pragma unroll
  for (int mi = 0; mi < 4; ++mi){
    int row = m0 + wr*64 + mi*16 + (l >> 4)*4;
    #pragma unroll
    for (int ni = 0; ni < 4; ++ni){
      int col = n0 + wc*64 + ni*16 + (l & 15);
      float bb = bias ? bias[col] : 0.0f;
      #pragma unroll
      for (int r = 0; r < 4; ++r)
        Cc[(size_t)(row + r)*N + col] = acc[mi][ni][r] + bb;
    }
  }
}

// ---------------------------------------------------------------------------
// Persistent loop kernel. blk -> (b = blk&31, sub = blk>>5) for attention;
// blk owns j-pair {2blk, 2blk+1} x 4 gates for LSTM (weights in LDS, x staged
// in LDS per 16-batch half). WhT slice in registers. All sync relaxed.
// s_part packed per-(b,sub): s_part[(b*8+sub)*200 + p] (contiguous writes).
__global__ __launch_bounds__(512, 1) void loop_kernel(
    const float* __restrict__ feats, const float* __restrict__ feat_proj,
    const float* __restrict__ WhT, const float* __restrict__ attn_b,
    const float* __restrict__ v_w, const float* __restrict__ emb,
    const float* __restrict__ W_ih, const float* __restrict__ W_hh,
    const float* __restrict__ b_ih, const float* __restrict__ b_hh,
    float* __restrict__ hbuf0, float* __restrict__ hbuf1,
    const float* __restrict__ c_init,
    float* __restrict__ ctx_g, float* __restrict__ s_part,
    unsigned short* __restrict__ hall_h, unsigned short* __restrict__ hall_l,
    unsigned* __restrict__ fm, unsigned* __restrict__ fg1, unsigned* __restrict__ fg2)
{
  __shared__ float Wl[8][1540];    // 49.3KB gate weights [Wih(1024)|Whh(512)]
  __shared__ float xs[16][1540];   // 98.6KB staged x [emb|ctx|h] for 16 batches
  __shared__ float hs[512];
  __shared__ float hwl[64];
  __shared__ float partA[8][72];
  __shared__ float scr[256];
  __shared__ float aux[256];
  __shared__ float bias8[8];
  __shared__ float smx, sinv;

  const int blk = blockIdx.x, tid = threadIdx.x;
  const int b = blk & 31, sub = blk >> 5;
  const int jb = blk*2;
  const int l = tid & 63, wv = tid >> 6;

  // ---- prologue: gate weights -> LDS, WhT slice -> registers ----
  #pragma unroll
  for (int r = 0; r < 8; ++r){
    const int col = (r >> 1)*512 + jb + (r & 1);
    const float4* wi = (const float4*)(W_ih + (size_t)col*1024);
    const float4* wh = (const float4*)(W_hh + (size_t)col*512);
    float4* d0 = (float4*)&Wl[r][0];
    float4* d1 = (float4*)&Wl[r][1024];
    for (int q = tid; q < 256; q += NT) d0[q] = wi[q];
    for (int q = tid; q < 128; q += NT) d1[q] = wh[q];
  }
  float wreg[64];
  #pragma unroll
  for (int kk = 0; kk < 64; ++kk)
    wreg[kk] = WhT[(size_t)(wv*64 + kk)*512 + sub*64 + l];
  if (tid < 8){
    const int col = (tid >> 1)*512 + jb + (tid & 1);
    bias8[tid] = b_ih[col] + b_hh[col];
  }
  const float vl = v_w[sub*64 + l];
  const float ab = (tid < 64) ? attn_b[sub*64 + tid] : 0.f;
  float cA = 0.f, cB = 0.f;      // c-state for (bb=tid>>1, jj=tid&1), halves 0/1
  if (tid < 32){
    cA = c_init[(tid >> 1)*512 + jb + (tid & 1)];
    cB = c_init[(16 + (tid >> 1))*512 + jb + (tid & 1)];
  }
  __syncthreads();

  for (int t = 0; t < T; ++t){
    const float* h_in  = (t & 1) ? hbuf1 : hbuf0;
    float*       h_out = (t & 1) ? hbuf0 : hbuf1;
    const unsigned gen = (unsigned)(t + 1);

    // ---- A: hWh[b][sub*64..+64) from register weights + LDS-broadcast h ----
    hs[tid] = cohload(h_in + b*512 + tid);
    __syncthreads();
    {
      const float* hk = hs + wv*64;
      float a = 0.f;
      #pragma unroll
      for (int kk = 0; kk < 64; ++kk) a += hk[kk] * wreg[kk];
      partA[wv][l] = a;
    }
    __syncthreads();
    if (tid < 64){
      float s = ab;
      #pragma unroll
      for (int k = 0; k < 8; ++k) s += partA[k][tid];
      hwl[tid] = s;
    }
    __syncthreads();

    // ---- B: partial scores over own j-slice (feat_proj from warm L2) ----
    {
      const float hj = hwl[l];
      for (int p = wv; p < P; p += 8){
        float fp = feat_proj[((size_t)b*P + p)*512 + sub*64 + l];
        float e2 = vl * fast_tanh(fp + hj);
        #pragma unroll
        for (int off = 32; off; off >>= 1) e2 += __shfl_xor(e2, off);
        if (l == 0) cohstore(s_part + (size_t)(b*8 + sub)*200 + p, e2);
      }
    }
    bar_flag(fm + b*8 + sub, fm + b*8, 8, gen);

    // ---- C: reduce partials -> softmax -> ctx slice (feats from warm L2) ----
    {
      float sc_v = -1e30f;
      if (tid < P){
        const float* sp = s_part + (size_t)b*8*200 + tid;
        float s8 = 0.f;
        #pragma unroll
        for (int k = 0; k < 8; ++k) s8 += cohload(sp + k*200);
        sc_v = s8;
      }
      if (tid < 256) aux[tid] = sc_v;
      __syncthreads();
      if (tid < 64){
        float m = -1e30f;
        #pragma unroll
        for (int i = 0; i < 4; ++i) m = fmaxf(m, aux[tid + i*64]);
        #pragma unroll
        for (int off = 32; off; off >>= 1) m = fmaxf(m, __shfl_xor(m, off));
        if (tid == 0) smx = m;
      }
      __syncthreads();
      float al = (tid < P) ? __expf(sc_v - smx) : 0.f;
      if (tid < 256) aux[tid] = al;
      __syncthreads();
      if (tid < 64){
        float s = 0.f;
        #pragma unroll
        for (int i = 0; i < 4; ++i) s += aux[tid + i*64];
        #pragma unroll
        for (int off = 32; off; off >>= 1) s += __shfl_xor(s, off);
        if (tid == 0) sinv = 1.0f/s;
      }
      __syncthreads();
      float a = 0.f;
      for (int p = wv; p < P; p += 8)
        a += aux[p] * feats[((size_t)b*P + p)*512 + sub*64 + l];
      partA[wv][l] = a;
      __syncthreads();
      if (tid < 64){
        float s = 0.f;
        #pragma unroll
        for (int k = 0; k < 8; ++k) s += partA[k][tid];
        cohstore(ctx_g + b*512 + sub*64 + tid, s * sinv);
      }
    }
    bar_flag(fg1 + blk, fg1, NB, gen);

    // ---- D: two 16-batch halves; stage x to LDS, dot from LDS ----
    #pragma unroll
    for (int half = 0; half < 2; ++half){
      const int b0 = half*16;
      // stage: emb plain f4 (L2-warm), ctx/h coherent scalars
      for (int q = tid; q < 2048; q += NT){
        const int bb = q >> 7, i = (q & 127)*4;
        *(float4*)&xs[bb][i] = *(const float4*)&emb[((size_t)(b0 + bb)*T + t)*512 + i];
      }
      for (int q = tid; q < 8192; q += NT){
        const int bb = q >> 9, i = q & 511;
        xs[bb][512 + i] = cohload(ctx_g + (b0 + bb)*512 + i);
      }
      for (int q = tid; q < 8192; q += NT){
        const int bb = q >> 9, i = q & 511;
        xs[bb][1024 + i] = cohload(h_in + (b0 + bb)*512 + i);
      }
      __syncthreads();
      // dots: tid<256: kh = tid>>7 (K half), o = tid&127: bb=o>>3, c=o&7
      if (tid < 256){
        const int kh = tid >> 7, o = tid & 127, bb = o >> 3, c = o & 7;
        const float4* xr = (const float4*)&xs[bb][kh*768];
        const float4* wr = (const float4*)&Wl[c][kh*768];
        float a0 = 0.f, a1 = 0.f;
        #pragma unroll 16
        for (int i = 0; i < 192; i += 2){
          a0 += dot4(wr[i], xr[i]);
          a1 += dot4(wr[i+1], xr[i+1]);
        }
        scr[tid] = a0 + a1;
      }
      __syncthreads();
      if (tid < 32){
        const int bb = tid >> 1, jj = tid & 1;
        float gv[4];
        #pragma unroll
        for (int g = 0; g < 4; ++g){
          const int c = g*2 + jj, o = bb*8 + c;
          gv[g] = scr[o] + scr[128 + o] + bias8[c];
        }
        const float i_ = sigmoidf_(gv[0]);
        const float f_ = sigmoidf_(gv[1]);
        const float g_ = fast_tanh(gv[2]);
        const float o_ = sigmoidf_(gv[3]);
        const int gb = b0 + bb, j = jb + jj;
        const float c_old = half ? cB : cA;
        const float c_new = f_*c_old + i_*g_;
        const float h_new = o_*fast_tanh(c_new);
        if (half) cB = c_new; else cA = c_new;
        cohstore(h_out + gb*512 + j, h_new);
        const unsigned short hh = f_to_bf16(h_new);
        hall_h[((size_t)gb*T + t)*512 + j] = hh;
        hall_l[((size_t)gb*T + t)*512 + j] = f_to_bf16(h_new - bf16_to_f(hh));
      }
      __syncthreads();
    }
    bar_flag(fg2 + blk, fg2, NB, gen);
  }
}

// ---------------------------------------------------------------------------
extern "C" void kernel_launch(void* const* d_in, const int* in_sizes, int n_in,
                              void* d_out, int out_size, void* d_ws, size_t ws_size,
                              hipStream_t stream)
{
  (void)in_sizes; (void)n_in; (void)out_size;
  const float* features = (const float*)d_in[0];
  const int*   captions = (const int*)d_in[1];
  const float* embed_W  = (const float*)d_in[2];
  const float* attn_W   = (const float*)d_in[3];
  const float* attn_b   = (const float*)d_in[4];
  const float* v_w      = (const float*)d_in[5];
  const float* W_ih     = (const float*)d_in[6];
  const float* W_hh     = (const float*)d_in[7];
  const float* b_ih     = (const float*)d_in[8];
  const float* b_hh     = (const float*)d_in[9];
  const float* lin_W    = (const float*)d_in[10];
  const float* lin_b    = (const float*)d_in[11];
  const float* inith_W  = (const float*)d_in[12];
  const float* inith_b  = (const float*)d_in[13];
  const float* initc_W  = (const float*)d_in[14];
  const float* initc_b  = (const float*)d_in[15];

  // "early" scratch in d_out (dead before final logits GEMM writes d_out)
  char* o = (char*)d_out;
  unsigned short* feat_bf   = (unsigned short*)o; o += (size_t)(B*P)*E*2;   // 6.4MB
  unsigned short* Wf_bf     = (unsigned short*)o; o += (size_t)H*E*2;       // 0.5MB
  float*          feat_proj = (float*)o;          o += (size_t)(B*P)*H*4;   // 12.9MB

  // persistent scratch in d_ws
  const size_t SZ_LIN  = (size_t)V*H*2;          // 32.77MB
  const size_t SZ_HALL = (size_t)(B*T)*H*2;      // 1MB
  const size_t SZ_EMB  = (size_t)(B*T)*E*4;      // 2.1MB
  const size_t SZ_ST   = (size_t)B*H*4;          // 64KB
  const size_t SZ_WHT  = (size_t)H*H*4;          // 1MB
  const size_t SZ_SP   = (size_t)B*8*200*4;      // 0.2MB
  const size_t SZ_FLG  = 4096;
  const size_t need_wo = SZ_LIN + 2*SZ_HALL + SZ_EMB + 5*SZ_ST + SZ_WHT + SZ_SP + SZ_FLG;
  const bool three = (ws_size >= need_wo + SZ_LIN);

  char* w = (char*)d_ws;
  unsigned short* lin_hi  = (unsigned short*)w; w += SZ_LIN;
  unsigned short* lin_lo  = (unsigned short*)w; if (three) w += SZ_LIN;
  unsigned short* hall_hi = (unsigned short*)w; w += SZ_HALL;
  unsigned short* hall_lo = (unsigned short*)w; w += SZ_HALL;
  float*          emb_ws  = (float*)w;          w += SZ_EMB;
  float*          hbuf0   = (float*)w;          w += SZ_ST;
  float*          hbuf1   = (float*)w;          w += SZ_ST;
  float*          c_state = (float*)w;          w += SZ_ST;
  float*          ctx_ws  = (float*)w;          w += SZ_ST;
  float*          WhT_ws  = (float*)w;          w += SZ_WHT;
  float*          spart   = (float*)w;          w += SZ_SP;
  unsigned*       flags   = (unsigned*)w;       w += SZ_FLG;
  unsigned* fm  = flags;          // [256] mini-barrier flags [b*8+sub]
  unsigned* fg1 = flags + 256;    // [256] grid barrier 1
  unsigned* fg2 = flags + 512;    // [256] grid barrier 2

  // --- conversions / gathers / init ---
  split_kernel<<<2048, 256, 0, stream>>>(features, E, 0, B*P, feat_bf, nullptr, E, 0);
  split_kernel<<<256, 256, 0, stream>>>(attn_W, E+H, 0, H, Wf_bf, nullptr, E, 0);
  split_kernel<<<2048, 256, 0, stream>>>(lin_W, 512, 0, V, lin_hi, three ? lin_lo : nullptr, 512, 0);
  embed_kernel<<<B*T, 128, 0, stream>>>(captions, embed_W, emb_ws);
  prep_kernel<<<B, 512, 0, stream>>>(features, inith_W, inith_b, initc_W, initc_b,
                                     hbuf0, c_state);
  transpose_wh_kernel<<<64, 256, 0, stream>>>(attn_W, WhT_ws);
  hipMemsetAsync(flags, 0, SZ_FLG, stream);

  // feat_proj = features @ Wf^T (bf16 1-pass; error damped through tanh/softmax)
  gemm_bt_kernel<<<(B*P/128)*(E/128), 256, 0, stream>>>(
      feat_bf, feat_bf, feat_bf, Wf_bf, Wf_bf, Wf_bf,
      feat_proj, nullptr, E, E, 1, B*P/128, 0);

  // --- the whole recurrence in one persistent kernel ---
  loop_kernel<<<NB, NT, 0, stream>>>(
      features, feat_proj, WhT_ws, attn_b, v_w, emb_ws, W_ih, W_hh, b_ih, b_hh,
      hbuf0, hbuf1, c_state, ctx_ws, spart, hall_hi, hall_lo, fm, fg1, fg2);

  // --- logits = h_all @ lin_W^T + lin_b (bf16x3, XCD-swizzled grid) ---
  gemm_bt_kernel<<<(V/128)*(B*T/128), 256, 0, stream>>>(
      hall_hi, hall_lo, hall_hi, lin_hi, lin_hi, three ? lin_lo : lin_hi,
      (float*)d_out, lin_b, V, H, three ? 3 : 2, B*T/128, 1);
}

// Round 10
// 1564.668 us; speedup vs baseline: 1.6445x; 1.3917x over previous
//
// CaptionDecoder on MI355X — round 10: cacheable cross-block exchange.
// r9 audit: the constant ~60us/step was phase D's 32K cohloads/block/step
// (uncacheable LLC broadcast) + an LDS-throughput-bound dot loop, not barrier
// mechanics. Fix: time-indexed write-once buffers (xcat[t][b][emb|ctx|h]) ->
// plain cached reads can never be stale; phase D register-blocked (2col x
// 4batch tiles); zero cohloads anywhere.
#include <hip/hip_runtime.h>

#define E 512
#define H 512
#define V 32000
#define B 32
#define P 196
#define T 32
#define NB 256
#define NT 512

typedef __attribute__((ext_vector_type(8))) short s8v;    // 8 bf16
typedef __attribute__((ext_vector_type(4))) float f4v;    // 4 f32 acc

__device__ __forceinline__ float bf16_to_f(unsigned short u){
  return __uint_as_float(((unsigned)u) << 16);
}
__device__ __forceinline__ unsigned short f_to_bf16(float f){
  unsigned u = __float_as_uint(f);
  u += 0x7FFFu + ((u >> 16) & 1u);   // RNE
  return (unsigned short)(u >> 16);
}
__device__ __forceinline__ float fast_tanh(float x){
  float e = __expf(2.0f*x);
  return 1.0f - 2.0f/(e + 1.0f);
}
__device__ __forceinline__ float sigmoidf_(float x){
  return 1.0f/(1.0f + __expf(-x));
}
__device__ __forceinline__ void load_lds16(const unsigned short* g, unsigned short* l){
  __builtin_amdgcn_global_load_lds(
      (const __attribute__((address_space(1))) void*)g,
      (__attribute__((address_space(3))) void*)l, 16, 0, 0);
}
__device__ __forceinline__ float dot4(float4 a, float4 b){
  return a.x*b.x + a.y*b.y + a.z*b.z + a.w*b.w;
}

#define AT_SCOPE __HIP_MEMORY_SCOPE_AGENT
// Coherent store for write-once cross-block data (readers use plain loads of
// never-before-cached addresses -> no staleness possible).
__device__ __forceinline__ void cohstore(float* p, float v){
  __hip_atomic_store(p, v, __ATOMIC_RELAXED, AT_SCOPE);
}

// Flag-array barrier, fully relaxed (r9-proven). __syncthreads drains vmcnt
// (block's coherent stores complete at LLC) before the flag publish.
__device__ __forceinline__ void bar_flag(unsigned* my, const unsigned* wait_base,
                                         int n, unsigned gen){
  __syncthreads();
  if (threadIdx.x == 0)
    __hip_atomic_store(my, gen, __ATOMIC_RELAXED, AT_SCOPE);
  if (threadIdx.x < 64){
    for (;;){
      unsigned mn = 0xffffffffu;
      for (int i = (int)threadIdx.x; i < n; i += 64){
        unsigned v = __hip_atomic_load(wait_base + i, __ATOMIC_RELAXED, AT_SCOPE);
        mn = v < mn ? v : mn;
      }
      #pragma unroll
      for (int off = 32; off; off >>= 1){
        unsigned o2 = (unsigned)__shfl_xor((int)mn, off);
        mn = o2 < mn ? o2 : mn;
      }
      if (mn >= gen) break;
      __builtin_amdgcn_s_sleep(1);
    }
    __builtin_amdgcn_sched_barrier(0);
  }
  __syncthreads();
}

// ---------------------------------------------------------------------------
// f32 (strided) -> bf16 hi (+ optional lo residual). cols==512.
__global__ void split_kernel(const float* __restrict__ src, int src_ld, int src_coff,
                             int rows,
                             unsigned short* __restrict__ dhi, unsigned short* __restrict__ dlo,
                             int dst_ld, int dst_coff)
{
  int n = rows << 9;
  for (int i = blockIdx.x*blockDim.x + threadIdx.x; i < n; i += gridDim.x*blockDim.x){
    int r = i >> 9, c = i & 511;
    float x = src[(size_t)r*src_ld + src_coff + c];
    unsigned short h = f_to_bf16(x);
    dhi[(size_t)r*dst_ld + dst_coff + c] = h;
    if (dlo) dlo[(size_t)r*dst_ld + dst_coff + c] = f_to_bf16(x - bf16_to_f(h));
  }
}

// Embedding gather -> xcat[t][b][0:512]
__global__ void embed_kernel(const int* __restrict__ caps, const float* __restrict__ embW,
                             float* __restrict__ xcat)
{
  int row = blockIdx.x;            // row = b*T + t
  int b = row >> 5, t = row & 31;  // T == 32
  int cap = caps[row];
  const float4* s = (const float4*)(embW + (size_t)cap*E);
  float4* d = (float4*)(xcat + (size_t)(t*B + b)*1536);
  for (int e = threadIdx.x; e < E/4; e += blockDim.x) d[e] = s[e];
}

// mean over P, then h0 -> xcat[0][b][1024:1536], c0 -> c_state
__global__ __launch_bounds__(512) void prep_kernel(
    const float* __restrict__ feats,
    const float* __restrict__ inith_W, const float* __restrict__ inith_b,
    const float* __restrict__ initc_W, const float* __restrict__ initc_b,
    float* __restrict__ xcat, float* __restrict__ c_state)
{
  __shared__ float mf[E];
  const int b = blockIdx.x, tid = threadIdx.x;
  const float* fb = feats + (size_t)b*P*E + tid;
  float s = 0.f;
  for (int p = 0; p < P; ++p) s += fb[(size_t)p*E];
  mf[tid] = s * (1.0f/196.0f);
  __syncthreads();
  const float* wh = inith_W + (size_t)tid*E;
  const float* wc = initc_W + (size_t)tid*E;
  float h0 = inith_b[tid], c0 = initc_b[tid];
  #pragma unroll 4
  for (int e = 0; e < E; e += 4){
    float4 a4 = *(const float4*)(wh + e);
    float4 b4 = *(const float4*)(wc + e);
    float4 m4 = *(const float4*)(mf + e);
    h0 += dot4(a4, m4);
    c0 += dot4(b4, m4);
  }
  xcat[(size_t)b*1536 + 1024 + tid] = h0;
  c_state[b*H + tid] = c0;
}

// WhT[k][j] = attn_W[j][E + k]
__global__ __launch_bounds__(256) void transpose_wh_kernel(
    const float* __restrict__ attn_W, float* __restrict__ WhT)
{
  __shared__ float tile[64][65];
  const int jt = blockIdx.x & 7, kt = blockIdx.x >> 3;
  const int tx = threadIdx.x & 63, ty = threadIdx.x >> 6;
  for (int r = ty; r < 64; r += 4)
    tile[r][tx] = attn_W[(size_t)(jt*64 + r)*(E+H) + E + kt*64 + tx];
  __syncthreads();
  for (int r = ty; r < 64; r += 4)
    WhT[(size_t)(kt*64 + r)*512 + jt*64 + tx] = tile[tx][r];
}

// ---------------------------------------------------------------------------
// m97-style bf16 GEMM: C = sum_passes A_p (MxK) * B_p(NxK)^T [+bias]
__global__ __launch_bounds__(256) void gemm_bt_kernel(
    const unsigned short* __restrict__ A0, const unsigned short* __restrict__ A1,
    const unsigned short* __restrict__ A2,
    const unsigned short* __restrict__ B0, const unsigned short* __restrict__ B1,
    const unsigned short* __restrict__ B2,
    float* __restrict__ Cc, const float* __restrict__ bias,
    int N, int K, int npasses, int mt, int swz)
{
  __shared__ __align__(16) unsigned short Al[128*32];
  __shared__ __align__(16) unsigned short Bl[128*32];
  const int tid = threadIdx.x;
  const int wid = tid >> 6, l = tid & 63;
  int f = blockIdx.x;
  if (swz) f = (f & 7)*((int)gridDim.x >> 3) + (f >> 3);
  const int m0 = (f % mt)*128, n0 = (f / mt)*128;
  const int wr = wid >> 1, wc = wid & 1;

  f4v acc[4][4];
  #pragma unroll
  for (int i = 0; i < 4; ++i)
    #pragma unroll
    for (int j = 0; j < 4; ++j) acc[i][j] = (f4v){0.f,0.f,0.f,0.f};

  const int s0 = tid, s1 = tid + 256;
  const int r0 = s0 >> 2, g0 = (s0 & 3) ^ ((r0 >> 1) & 3);
  const int r1 = s1 >> 2, g1 = (s1 & 3) ^ ((r1 >> 1) & 3);
  const int la = l & 15, ch = l >> 4;

  for (int pass = 0; pass < npasses; ++pass){
    const unsigned short* Ap = pass == 0 ? A0 : (pass == 1 ? A1 : A2);
    const unsigned short* Bp = pass == 0 ? B0 : (pass == 1 ? B1 : B2);
    for (int k0 = 0; k0 < K; k0 += 32){
      __syncthreads();
      load_lds16(Ap + (size_t)(m0 + r0)*K + k0 + g0*8, Al + s0*8);
      load_lds16(Ap + (size_t)(m0 + r1)*K + k0 + g1*8, Al + s1*8);
      load_lds16(Bp + (size_t)(n0 + r0)*K + k0 + g0*8, Bl + s0*8);
      load_lds16(Bp + (size_t)(n0 + r1)*K + k0 + g1*8, Bl + s1*8);
      __syncthreads();
      s8v av[4], bv[4];
      #pragma unroll
      for (int mi = 0; mi < 4; ++mi){
        int row = wr*64 + mi*16 + la;
        int cs = ch ^ ((row >> 1) & 3);
        av[mi] = *(const s8v*)(Al + (row*4 + cs)*8);
      }
      #pragma unroll
      for (int ni = 0; ni < 4; ++ni){
        int row = wc*64 + ni*16 + la;
        int cs = ch ^ ((row >> 1) & 3);
        bv[ni] = *(const s8v*)(Bl + (row*4 + cs)*8);
      }
      #pragma unroll
      for (int mi = 0; mi < 4; ++mi)
        #pragma unroll
        for (int ni = 0; ni < 4; ++ni)
          acc[mi][ni] = __builtin_amdgcn_mfma_f32_16x16x32_bf16(av[mi], bv[ni], acc[mi][ni], 0, 0, 0);
    }
  }
  #pragma unroll
  for (int mi = 0; mi < 4; ++mi){
    int row = m0 + wr*64 + mi*16 + (l >> 4)*4;
    #pragma unroll
    for (int ni = 0; ni < 4; ++ni){
      int col = n0 + wc*64 + ni*16 + (l & 15);
      float bb = bias ? bias[col] : 0.0f;
      #pragma unroll
      for (int r = 0; r < 4; ++r)
        Cc[(size_t)(row + r)*N + col] = acc[mi][ni][r] + bb;
    }
  }
}

// ---------------------------------------------------------------------------
// Persistent loop kernel. blk -> (b = blk&31, sub = blk>>5) for attention;
// blk owns j-pair {2blk, 2blk+1} x 4 gates for phase D (weights in LDS).
// All cross-block exchange: write-once time-indexed buffers, coherent stores,
// PLAIN cached reads. Per step: [A+B] mini8 [C] grid [D] grid.
__global__ __launch_bounds__(512, 1) void loop_kernel(
    const float* __restrict__ feats, const float* __restrict__ feat_proj,
    const float* __restrict__ WhT, const float* __restrict__ attn_b,
    const float* __restrict__ v_w,
    const float* __restrict__ W_ih, const float* __restrict__ W_hh,
    const float* __restrict__ b_ih, const float* __restrict__ b_hh,
    float* __restrict__ xcat,          // [T+1][B][1536]: emb|ctx|h
    const float* __restrict__ c_init,
    float* __restrict__ sps,           // [T][B][8][200]
    unsigned short* __restrict__ hall_h, unsigned short* __restrict__ hall_l,
    unsigned* __restrict__ fm, unsigned* __restrict__ fg1, unsigned* __restrict__ fg2)
{
  __shared__ float Wl[8][1540];    // 49.3KB gate weights [Wih(1024)|Whh(512)]
  __shared__ float red[4096];      // 16KB phase-D reduction scratch
  __shared__ float hs[512];
  __shared__ float hwl[64];
  __shared__ float partA[8][72];
  __shared__ float aux[256];
  __shared__ float bias8[8];
  __shared__ float smx, sinv;

  const int blk = blockIdx.x, tid = threadIdx.x;
  const int b = blk & 31, sub = blk >> 5;
  const int jb = blk*2;
  const int l = tid & 63, wv = tid >> 6;

  // ---- prologue: gate weights -> LDS, WhT slice -> registers ----
  #pragma unroll
  for (int r = 0; r < 8; ++r){
    const int col = (r >> 1)*512 + jb + (r & 1);
    const float4* wi = (const float4*)(W_ih + (size_t)col*1024);
    const float4* wh = (const float4*)(W_hh + (size_t)col*512);
    float4* d0 = (float4*)&Wl[r][0];
    float4* d1 = (float4*)&Wl[r][1024];
    for (int q = tid; q < 256; q += NT) d0[q] = wi[q];
    for (int q = tid; q < 128; q += NT) d1[q] = wh[q];
  }
  float wreg[64];
  #pragma unroll
  for (int kk = 0; kk < 64; ++kk)
    wreg[kk] = WhT[(size_t)(wv*64 + kk)*512 + sub*64 + l];
  if (tid < 8){
    const int col = (tid >> 1)*512 + jb + (tid & 1);
    bias8[tid] = b_ih[col] + b_hh[col];
  }
  const float vl = v_w[sub*64 + l];
  const float ab = (tid < 64) ? attn_b[sub*64 + tid] : 0.f;
  float c_reg = 0.f;               // tid<64 owns (bb=tid>>1, jj=tid&1)
  if (tid < 64) c_reg = c_init[(tid >> 1)*512 + jb + (tid & 1)];

  // phase-D tile decomposition (constant per thread)
  const int kseg = tid >> 5;               // 16 K-segments of 96
  const int bq   = (tid & 31) >> 2;        // 8 batch-quads
  const int cp   = tid & 3;                // 4 col-pairs
  const int k0   = kseg*96;
  __syncthreads();

  for (int t = 0; t < T; ++t){
    const float* xin  = xcat + (size_t)t*B*1536;        // this step's x rows
    float*       xout = xcat + (size_t)(t+1)*B*1536;    // next step's h slot
    const unsigned gen = (unsigned)(t + 1);

    // ---- A: hWh[b][sub*64..+64) from register weights + LDS-broadcast h ----
    hs[tid] = xin[(size_t)b*1536 + 1024 + tid];
    __syncthreads();
    {
      const float* hk = hs + wv*64;
      float a = 0.f;
      #pragma unroll
      for (int kk = 0; kk < 64; ++kk) a += hk[kk] * wreg[kk];
      partA[wv][l] = a;
    }
    __syncthreads();
    if (tid < 64){
      float s = ab;
      #pragma unroll
      for (int k = 0; k < 8; ++k) s += partA[k][tid];
      hwl[tid] = s;
    }
    __syncthreads();

    // ---- B: partial scores over own j-slice (feat_proj from warm L2) ----
    {
      const float hj = hwl[l];
      float* spw = sps + ((size_t)(t*B + b)*8 + sub)*200;
      for (int p = wv; p < P; p += 8){
        float fp = feat_proj[((size_t)b*P + p)*512 + sub*64 + l];
        float e2 = vl * fast_tanh(fp + hj);
        #pragma unroll
        for (int off = 32; off; off >>= 1) e2 += __shfl_xor(e2, off);
        if (l == 0) cohstore(spw + p, e2);
      }
    }
    bar_flag(fm + b*8 + sub, fm + b*8, 8, gen);

    // ---- C: reduce partials -> softmax -> ctx slice (all plain reads) ----
    {
      float sc_v = -1e30f;
      if (tid < P){
        const float* sp = sps + (size_t)(t*B + b)*8*200 + tid;
        float s8 = 0.f;
        #pragma unroll
        for (int k = 0; k < 8; ++k) s8 += sp[k*200];
        sc_v = s8;
      }
      if (tid < 256) aux[tid] = sc_v;
      __syncthreads();
      if (tid < 64){
        float m = -1e30f;
        #pragma unroll
        for (int i = 0; i < 4; ++i) m = fmaxf(m, aux[tid + i*64]);
        #pragma unroll
        for (int off = 32; off; off >>= 1) m = fmaxf(m, __shfl_xor(m, off));
        if (tid == 0) smx = m;
      }
      __syncthreads();
      float al = (tid < P) ? __expf(sc_v - smx) : 0.f;
      if (tid < 256) aux[tid] = al;
      __syncthreads();
      if (tid < 64){
        float s = 0.f;
        #pragma unroll
        for (int i = 0; i < 4; ++i) s += aux[tid + i*64];
        #pragma unroll
        for (int off = 32; off; off >>= 1) s += __shfl_xor(s, off);
        if (tid == 0) sinv = 1.0f/s;
      }
      __syncthreads();
      float a = 0.f;
      for (int p = wv; p < P; p += 8)
        a += aux[p] * feats[((size_t)b*P + p)*512 + sub*64 + l];
      partA[wv][l] = a;
      __syncthreads();
      if (tid < 64){
        float s = 0.f;
        #pragma unroll
        for (int k = 0; k < 8; ++k) s += partA[k][tid];
        cohstore(xcat + (size_t)(t*B + b)*1536 + 512 + sub*64 + tid, s * sinv);
      }
    }
    bar_flag(fg1 + blk, fg1, NB, gen);

    // ---- D: gates for 8 cols x 32 batches; 2col x 4batch register tiles ----
    {
      float a0[4], a1[4];
      #pragma unroll
      for (int u = 0; u < 4; ++u){ a0[u] = 0.f; a1[u] = 0.f; }
      const float4* w0 = (const float4*)&Wl[cp*2][k0];
      const float4* w1 = (const float4*)&Wl[cp*2 + 1][k0];
      const float* xb0 = xin + (size_t)(bq*4)*1536 + k0;
      #pragma unroll 6
      for (int i = 0; i < 24; ++i){
        const float4 wa = w0[i], wb = w1[i];
        #pragma unroll
        for (int u = 0; u < 4; ++u){
          const float4 xv = *(const float4*)(xb0 + (size_t)u*1536 + i*4);
          a0[u] += dot4(wa, xv);
          a1[u] += dot4(wb, xv);
        }
      }
      #pragma unroll
      for (int u = 0; u < 4; ++u){
        red[kseg*256 + (bq*4 + u)*8 + cp*2]     = a0[u];
        red[kseg*256 + (bq*4 + u)*8 + cp*2 + 1] = a1[u];
      }
    }
    __syncthreads();
    if (tid < 64){
      const int bb = tid >> 1, jj = tid & 1;
      float gv[4];
      #pragma unroll
      for (int g = 0; g < 4; ++g){
        const int c = g*2 + jj;
        float s = bias8[c];
        #pragma unroll
        for (int k = 0; k < 16; ++k) s += red[k*256 + bb*8 + c];
        gv[g] = s;
      }
      const float i_ = sigmoidf_(gv[0]);
      const float f_ = sigmoidf_(gv[1]);
      const float g_ = fast_tanh(gv[2]);
      const float o_ = sigmoidf_(gv[3]);
      const int j = jb + jj;
      const float c_new = f_*c_reg + i_*g_;
      const float h_new = o_*fast_tanh(c_new);
      c_reg = c_new;
      cohstore(xout + (size_t)bb*1536 + 1024 + j, h_new);
      const unsigned short hh = f_to_bf16(h_new);
      hall_h[((size_t)bb*T + t)*512 + j] = hh;
      hall_l[((size_t)bb*T + t)*512 + j] = f_to_bf16(h_new - bf16_to_f(hh));
    }
    bar_flag(fg2 + blk, fg2, NB, gen);
  }
}

// ---------------------------------------------------------------------------
extern "C" void kernel_launch(void* const* d_in, const int* in_sizes, int n_in,
                              void* d_out, int out_size, void* d_ws, size_t ws_size,
                              hipStream_t stream)
{
  (void)in_sizes; (void)n_in; (void)out_size;
  const float* features = (const float*)d_in[0];
  const int*   captions = (const int*)d_in[1];
  const float* embed_W  = (const float*)d_in[2];
  const float* attn_W   = (const float*)d_in[3];
  const float* attn_b   = (const float*)d_in[4];
  const float* v_w      = (const float*)d_in[5];
  const float* W_ih     = (const float*)d_in[6];
  const float* W_hh     = (const float*)d_in[7];
  const float* b_ih     = (const float*)d_in[8];
  const float* b_hh     = (const float*)d_in[9];
  const float* lin_W    = (const float*)d_in[10];
  const float* lin_b    = (const float*)d_in[11];
  const float* inith_W  = (const float*)d_in[12];
  const float* inith_b  = (const float*)d_in[13];
  const float* initc_W  = (const float*)d_in[14];
  const float* initc_b  = (const float*)d_in[15];

  // "early" scratch in d_out (dead before final logits GEMM writes d_out)
  char* o = (char*)d_out;
  unsigned short* feat_bf   = (unsigned short*)o; o += (size_t)(B*P)*E*2;   // 6.4MB
  unsigned short* Wf_bf     = (unsigned short*)o; o += (size_t)H*E*2;       // 0.5MB
  float*          feat_proj = (float*)o;          o += (size_t)(B*P)*H*4;   // 12.9MB

  // persistent scratch in d_ws
  const size_t SZ_LIN  = (size_t)V*H*2;               // 32.77MB
  const size_t SZ_HALL = (size_t)(B*T)*H*2;           // 1MB
  const size_t SZ_XCAT = (size_t)(T+1)*B*1536*4;      // 6.49MB
  const size_t SZ_SPS  = (size_t)T*B*8*200*4;         // 6.55MB
  const size_t SZ_ST   = (size_t)B*H*4;               // 64KB
  const size_t SZ_WHT  = (size_t)H*H*4;               // 1MB
  const size_t SZ_FLG  = 4096;
  const size_t need_wo = SZ_LIN + 2*SZ_HALL + SZ_XCAT + SZ_SPS + SZ_ST + SZ_WHT + SZ_FLG;
  const bool three = (ws_size >= need_wo + SZ_LIN);

  char* w = (char*)d_ws;
  unsigned short* lin_hi  = (unsigned short*)w; w += SZ_LIN;
  unsigned short* lin_lo  = (unsigned short*)w; if (three) w += SZ_LIN;
  unsigned short* hall_hi = (unsigned short*)w; w += SZ_HALL;
  unsigned short* hall_lo = (unsigned short*)w; w += SZ_HALL;
  float*          xcat    = (float*)w;          w += SZ_XCAT;
  float*          sps     = (float*)w;          w += SZ_SPS;
  float*          c_state = (float*)w;          w += SZ_ST;
  float*          WhT_ws  = (float*)w;          w += SZ_WHT;
  unsigned*       flags   = (unsigned*)w;       w += SZ_FLG;
  unsigned* fm  = flags;          // [256] mini-barrier flags [b*8+sub]
  unsigned* fg1 = flags + 256;    // [256] grid barrier 1
  unsigned* fg2 = flags + 512;    // [256] grid barrier 2

  // --- conversions / gathers / init ---
  split_kernel<<<2048, 256, 0, stream>>>(features, E, 0, B*P, feat_bf, nullptr, E, 0);
  split_kernel<<<256, 256, 0, stream>>>(attn_W, E+H, 0, H, Wf_bf, nullptr, E, 0);
  split_kernel<<<2048, 256, 0, stream>>>(lin_W, 512, 0, V, lin_hi, three ? lin_lo : nullptr, 512, 0);
  embed_kernel<<<B*T, 128, 0, stream>>>(captions, embed_W, xcat);
  prep_kernel<<<B, 512, 0, stream>>>(features, inith_W, inith_b, initc_W, initc_b,
                                     xcat, c_state);
  transpose_wh_kernel<<<64, 256, 0, stream>>>(attn_W, WhT_ws);
  hipMemsetAsync(flags, 0, SZ_FLG, stream);

  // feat_proj = features @ Wf^T (bf16 1-pass; error damped through tanh/softmax)
  gemm_bt_kernel<<<(B*P/128)*(E/128), 256, 0, stream>>>(
      feat_bf, feat_bf, feat_bf, Wf_bf, Wf_bf, Wf_bf,
      feat_proj, nullptr, E, E, 1, B*P/128, 0);

  // --- the whole recurrence in one persistent kernel ---
  loop_kernel<<<NB, NT, 0, stream>>>(
      features, feat_proj, WhT_ws, attn_b, v_w, W_ih, W_hh, b_ih, b_hh,
      xcat, c_state, sps, hall_hi, hall_lo, fm, fg1, fg2);

  // --- logits = h_all @ lin_W^T + lin_b (bf16x3, XCD-swizzled grid) ---
  gemm_bt_kernel<<<(V/128)*(B*T/128), 256, 0, stream>>>(
      hall_hi, hall_lo, hall_hi, lin_hi, lin_hi, three ? lin_lo : lin_hi,
      (float*)d_out, lin_b, V, H, three ? 3 : 2, B*T/128, 1);
}

// Round 11
// 1412.031 us; speedup vs baseline: 1.8223x; 1.1081x over previous
//
// CaptionDecoder on MI355X — round 11: scanner grid barrier (single-word poll).
// r10: arrival is parallel but 255 blocks poll 256 flag words flat-out ->
// coherence-fabric congestion is the ~15us/barrier. Fix: block0/wave0 scans
// flags and publishes ONE gdone word; everyone else polls that word with
// backoff. Also: red-store bank padding (16-way -> 8-way).
#include <hip/hip_runtime.h>

#define E 512
#define H 512
#define V 32000
#define B 32
#define P 196
#define T 32
#define NB 256
#define NT 512

typedef __attribute__((ext_vector_type(8))) short s8v;    // 8 bf16
typedef __attribute__((ext_vector_type(4))) float f4v;    // 4 f32 acc

__device__ __forceinline__ float bf16_to_f(unsigned short u){
  return __uint_as_float(((unsigned)u) << 16);
}
__device__ __forceinline__ unsigned short f_to_bf16(float f){
  unsigned u = __float_as_uint(f);
  u += 0x7FFFu + ((u >> 16) & 1u);   // RNE
  return (unsigned short)(u >> 16);
}
__device__ __forceinline__ float fast_tanh(float x){
  float e = __expf(2.0f*x);
  return 1.0f - 2.0f/(e + 1.0f);
}
__device__ __forceinline__ float sigmoidf_(float x){
  return 1.0f/(1.0f + __expf(-x));
}
__device__ __forceinline__ void load_lds16(const unsigned short* g, unsigned short* l){
  __builtin_amdgcn_global_load_lds(
      (const __attribute__((address_space(1))) void*)g,
      (__attribute__((address_space(3))) void*)l, 16, 0, 0);
}
__device__ __forceinline__ float dot4(float4 a, float4 b){
  return a.x*b.x + a.y*b.y + a.z*b.z + a.w*b.w;
}

#define AT_SCOPE __HIP_MEMORY_SCOPE_AGENT
__device__ __forceinline__ void cohstore(float* p, float v){
  __hip_atomic_store(p, v, __ATOMIC_RELAXED, AT_SCOPE);
}
__device__ __forceinline__ unsigned cohldu(const unsigned* p){
  return __hip_atomic_load(p, __ATOMIC_RELAXED, AT_SCOPE);
}
__device__ __forceinline__ void cohstu(unsigned* p, unsigned v){
  __hip_atomic_store(p, v, __ATOMIC_RELAXED, AT_SCOPE);
}

// Mini-barrier among n<=8 blocks (XCD-local): poll n flags, relaxed.
__device__ __forceinline__ void bar_mini(unsigned* my, const unsigned* base,
                                         int n, unsigned gen){
  __syncthreads();
  if (threadIdx.x == 0) cohstu(my, gen);
  if (threadIdx.x < 64){
    for (;;){
      unsigned mn = 0xffffffffu;
      for (int i = (int)threadIdx.x; i < n; i += 64){
        unsigned v = cohldu(base + i);
        mn = v < mn ? v : mn;
      }
      #pragma unroll
      for (int off = 32; off; off >>= 1){
        unsigned o2 = (unsigned)__shfl_xor((int)mn, off);
        mn = o2 < mn ? o2 : mn;
      }
      if (mn >= gen) break;
      __builtin_amdgcn_s_sleep(2);
    }
    __builtin_amdgcn_sched_barrier(0);
  }
  __syncthreads();
}

// Grid barrier: parallel flag arrival; block 0 wave 0 scans and publishes one
// gdone word; all blocks poll only gdone (lane 0, with backoff).
__device__ __forceinline__ void bar_grid(unsigned* flags, unsigned* gdone,
                                         unsigned gen){
  __syncthreads();
  if (threadIdx.x == 0) cohstu(flags + blockIdx.x, gen);
  if (blockIdx.x == 0 && threadIdx.x < 64){
    for (;;){
      unsigned mn = 0xffffffffu;
      #pragma unroll
      for (int i = 0; i < 4; ++i){
        unsigned v = cohldu(flags + threadIdx.x + i*64);
        mn = v < mn ? v : mn;
      }
      #pragma unroll
      for (int off = 32; off; off >>= 1){
        unsigned o2 = (unsigned)__shfl_xor((int)mn, off);
        mn = o2 < mn ? o2 : mn;
      }
      if (mn >= gen) break;
      __builtin_amdgcn_s_sleep(1);
    }
    if (threadIdx.x == 0) cohstu(gdone, gen);
  }
  if (threadIdx.x == 0){
    while (cohldu(gdone) < gen) __builtin_amdgcn_s_sleep(4);
    __builtin_amdgcn_sched_barrier(0);
  }
  __syncthreads();
}

// ---------------------------------------------------------------------------
// f32 (strided) -> bf16 hi (+ optional lo residual). cols==512.
__global__ void split_kernel(const float* __restrict__ src, int src_ld, int src_coff,
                             int rows,
                             unsigned short* __restrict__ dhi, unsigned short* __restrict__ dlo,
                             int dst_ld, int dst_coff)
{
  int n = rows << 9;
  for (int i = blockIdx.x*blockDim.x + threadIdx.x; i < n; i += gridDim.x*blockDim.x){
    int r = i >> 9, c = i & 511;
    float x = src[(size_t)r*src_ld + src_coff + c];
    unsigned short h = f_to_bf16(x);
    dhi[(size_t)r*dst_ld + dst_coff + c] = h;
    if (dlo) dlo[(size_t)r*dst_ld + dst_coff + c] = f_to_bf16(x - bf16_to_f(h));
  }
}

// Embedding gather -> xcat[t][b][0:512]
__global__ void embed_kernel(const int* __restrict__ caps, const float* __restrict__ embW,
                             float* __restrict__ xcat)
{
  int row = blockIdx.x;            // row = b*T + t
  int b = row >> 5, t = row & 31;  // T == 32
  int cap = caps[row];
  const float4* s = (const float4*)(embW + (size_t)cap*E);
  float4* d = (float4*)(xcat + (size_t)(t*B + b)*1536);
  for (int e = threadIdx.x; e < E/4; e += blockDim.x) d[e] = s[e];
}

// mean over P, then h0 -> xcat[0][b][1024:1536], c0 -> c_state
__global__ __launch_bounds__(512) void prep_kernel(
    const float* __restrict__ feats,
    const float* __restrict__ inith_W, const float* __restrict__ inith_b,
    const float* __restrict__ initc_W, const float* __restrict__ initc_b,
    float* __restrict__ xcat, float* __restrict__ c_state)
{
  __shared__ float mf[E];
  const int b = blockIdx.x, tid = threadIdx.x;
  const float* fb = feats + (size_t)b*P*E + tid;
  float s = 0.f;
  for (int p = 0; p < P; ++p) s += fb[(size_t)p*E];
  mf[tid] = s * (1.0f/196.0f);
  __syncthreads();
  const float* wh = inith_W + (size_t)tid*E;
  const float* wc = initc_W + (size_t)tid*E;
  float h0 = inith_b[tid], c0 = initc_b[tid];
  #pragma unroll 4
  for (int e = 0; e < E; e += 4){
    float4 a4 = *(const float4*)(wh + e);
    float4 b4 = *(const float4*)(wc + e);
    float4 m4 = *(const float4*)(mf + e);
    h0 += dot4(a4, m4);
    c0 += dot4(b4, m4);
  }
  xcat[(size_t)b*1536 + 1024 + tid] = h0;
  c_state[b*H + tid] = c0;
}

// WhT[k][j] = attn_W[j][E + k]
__global__ __launch_bounds__(256) void transpose_wh_kernel(
    const float* __restrict__ attn_W, float* __restrict__ WhT)
{
  __shared__ float tile[64][65];
  const int jt = blockIdx.x & 7, kt = blockIdx.x >> 3;
  const int tx = threadIdx.x & 63, ty = threadIdx.x >> 6;
  for (int r = ty; r < 64; r += 4)
    tile[r][tx] = attn_W[(size_t)(jt*64 + r)*(E+H) + E + kt*64 + tx];
  __syncthreads();
  for (int r = ty; r < 64; r += 4)
    WhT[(size_t)(kt*64 + r)*512 + jt*64 + tx] = tile[tx][r];
}

// ---------------------------------------------------------------------------
// m97-style bf16 GEMM: C = sum_passes A_p (MxK) * B_p(NxK)^T [+bias]
__global__ __launch_bounds__(256) void gemm_bt_kernel(
    const unsigned short* __restrict__ A0, const unsigned short* __restrict__ A1,
    const unsigned short* __restrict__ A2,
    const unsigned short* __restrict__ B0, const unsigned short* __restrict__ B1,
    const unsigned short* __restrict__ B2,
    float* __restrict__ Cc, const float* __restrict__ bias,
    int N, int K, int npasses, int mt, int swz)
{
  __shared__ __align__(16) unsigned short Al[128*32];
  __shared__ __align__(16) unsigned short Bl[128*32];
  const int tid = threadIdx.x;
  const int wid = tid >> 6, l = tid & 63;
  int f = blockIdx.x;
  if (swz) f = (f & 7)*((int)gridDim.x >> 3) + (f >> 3);
  const int m0 = (f % mt)*128, n0 = (f / mt)*128;
  const int wr = wid >> 1, wc = wid & 1;

  f4v acc[4][4];
  #pragma unroll
  for (int i = 0; i < 4; ++i)
    #pragma unroll
    for (int j = 0; j < 4; ++j) acc[i][j] = (f4v){0.f,0.f,0.f,0.f};

  const int s0 = tid, s1 = tid + 256;
  const int r0 = s0 >> 2, g0 = (s0 & 3) ^ ((r0 >> 1) & 3);
  const int r1 = s1 >> 2, g1 = (s1 & 3) ^ ((r1 >> 1) & 3);
  const int la = l & 15, ch = l >> 4;

  for (int pass = 0; pass < npasses; ++pass){
    const unsigned short* Ap = pass == 0 ? A0 : (pass == 1 ? A1 : A2);
    const unsigned short* Bp = pass == 0 ? B0 : (pass == 1 ? B1 : B2);
    for (int k0 = 0; k0 < K; k0 += 32){
      __syncthreads();
      load_lds16(Ap + (size_t)(m0 + r0)*K + k0 + g0*8, Al + s0*8);
      load_lds16(Ap + (size_t)(m0 + r1)*K + k0 + g1*8, Al + s1*8);
      load_lds16(Bp + (size_t)(n0 + r0)*K + k0 + g0*8, Bl + s0*8);
      load_lds16(Bp + (size_t)(n0 + r1)*K + k0 + g1*8, Bl + s1*8);
      __syncthreads();
      s8v av[4], bv[4];
      #pragma unroll
      for (int mi = 0; mi < 4; ++mi){
        int row = wr*64 + mi*16 + la;
        int cs = ch ^ ((row >> 1) & 3);
        av[mi] = *(const s8v*)(Al + (row*4 + cs)*8);
      }
      #pragma unroll
      for (int ni = 0; ni < 4; ++ni){
        int row = wc*64 + ni*16 + la;
        int cs = ch ^ ((row >> 1) & 3);
        bv[ni] = *(const s8v*)(Bl + (row*4 + cs)*8);
      }
      #pragma unroll
      for (int mi = 0; mi < 4; ++mi)
        #pragma unroll
        for (int ni = 0; ni < 4; ++ni)
          acc[mi][ni] = __builtin_amdgcn_mfma_f32_16x16x32_bf16(av[mi], bv[ni], acc[mi][ni], 0, 0, 0);
    }
  }
  #pragma unroll
  for (int mi = 0; mi < 4; ++mi){
    int row = m0 + wr*64 + mi*16 + (l >> 4)*4;
    #pragma unroll
    for (int ni = 0; ni < 4; ++ni){
      int col = n0 + wc*64 + ni*16 + (l & 15);
      float bb = bias ? bias[col] : 0.0f;
      #pragma unroll
      for (int r = 0; r < 4; ++r)
        Cc[(size_t)(row + r)*N + col] = acc[mi][ni][r] + bb;
    }
  }
}

// ---------------------------------------------------------------------------
// Persistent loop kernel. blk = sub*32 + b: (b, sub) for attention (the 8
// sub-blocks of a batch share an XCD -> mini-barrier is XCD-local);
// blk owns j-pair {2blk, 2blk+1} x 4 gates for phase D (weights in LDS).
// Cross-block exchange: time-indexed write-once buffers, coherent stores,
// plain cached reads. Per step: [A+B] mini8 [C] grid [D] grid.
__global__ __launch_bounds__(512, 1) void loop_kernel(
    const float* __restrict__ feats, const float* __restrict__ feat_proj,
    const float* __restrict__ WhT, const float* __restrict__ attn_b,
    const float* __restrict__ v_w,
    const float* __restrict__ W_ih, const float* __restrict__ W_hh,
    const float* __restrict__ b_ih, const float* __restrict__ b_hh,
    float* __restrict__ xcat,          // [T+1][B][1536]: emb|ctx|h
    const float* __restrict__ c_init,
    float* __restrict__ sps,           // [T][B][8][200]
    unsigned short* __restrict__ hall_h, unsigned short* __restrict__ hall_l,
    unsigned* __restrict__ fm, unsigned* __restrict__ fg1, unsigned* __restrict__ fg2,
    unsigned* __restrict__ gd1, unsigned* __restrict__ gd2)
{
  __shared__ float Wl[8][1540];    // 49.3KB gate weights [Wih(1024)|Whh(512)]
  __shared__ float red[4224];      // 16.5KB phase-D reduction (kseg*264 pad)
  __shared__ float hs[512];
  __shared__ float hwl[64];
  __shared__ float partA[8][72];
  __shared__ float aux[256];
  __shared__ float bias8[8];
  __shared__ float smx, sinv;

  const int blk = blockIdx.x, tid = threadIdx.x;
  const int b = blk & 31, sub = blk >> 5;
  const int jb = blk*2;
  const int l = tid & 63, wv = tid >> 6;

  // ---- prologue: gate weights -> LDS, WhT slice -> registers ----
  #pragma unroll
  for (int r = 0; r < 8; ++r){
    const int col = (r >> 1)*512 + jb + (r & 1);
    const float4* wi = (const float4*)(W_ih + (size_t)col*1024);
    const float4* wh = (const float4*)(W_hh + (size_t)col*512);
    float4* d0 = (float4*)&Wl[r][0];
    float4* d1 = (float4*)&Wl[r][1024];
    for (int q = tid; q < 256; q += NT) d0[q] = wi[q];
    for (int q = tid; q < 128; q += NT) d1[q] = wh[q];
  }
  float wreg[64];
  #pragma unroll
  for (int kk = 0; kk < 64; ++kk)
    wreg[kk] = WhT[(size_t)(wv*64 + kk)*512 + sub*64 + l];
  if (tid < 8){
    const int col = (tid >> 1)*512 + jb + (tid & 1);
    bias8[tid] = b_ih[col] + b_hh[col];
  }
  const float vl = v_w[sub*64 + l];
  const float ab = (tid < 64) ? attn_b[sub*64 + tid] : 0.f;
  float c_reg = 0.f;               // tid<64 owns (bb=tid>>1, jj=tid&1)
  if (tid < 64) c_reg = c_init[(tid >> 1)*512 + jb + (tid & 1)];

  // phase-D tile decomposition (constant per thread)
  const int kseg = tid >> 5;               // 16 K-segments of 96
  const int bq   = (tid & 31) >> 2;        // 8 batch-quads
  const int cp   = tid & 3;                // 4 col-pairs
  const int k0   = kseg*96;
  __syncthreads();

  for (int t = 0; t < T; ++t){
    const float* xin  = xcat + (size_t)t*B*1536;
    float*       xout = xcat + (size_t)(t+1)*B*1536;
    const unsigned gen = (unsigned)(t + 1);

    // ---- A: hWh[b][sub*64..+64) from register weights + LDS-broadcast h ----
    hs[tid] = xin[(size_t)b*1536 + 1024 + tid];
    __syncthreads();
    {
      const float* hk = hs + wv*64;
      float a = 0.f;
      #pragma unroll
      for (int kk = 0; kk < 64; ++kk) a += hk[kk] * wreg[kk];
      partA[wv][l] = a;
    }
    __syncthreads();
    if (tid < 64){
      float s = ab;
      #pragma unroll
      for (int k = 0; k < 8; ++k) s += partA[k][tid];
      hwl[tid] = s;
    }
    __syncthreads();

    // ---- B: partial scores over own j-slice (feat_proj from warm L2) ----
    {
      const float hj = hwl[l];
      float* spw = sps + ((size_t)(t*B + b)*8 + sub)*200;
      for (int p = wv; p < P; p += 8){
        float fp = feat_proj[((size_t)b*P + p)*512 + sub*64 + l];
        float e2 = vl * fast_tanh(fp + hj);
        #pragma unroll
        for (int off = 32; off; off >>= 1) e2 += __shfl_xor(e2, off);
        if (l == 0) cohstore(spw + p, e2);
      }
    }
    bar_mini(fm + b*8 + sub, fm + b*8, 8, gen);

    // ---- C: reduce partials -> softmax -> ctx slice (all plain reads) ----
    {
      float sc_v = -1e30f;
      if (tid < P){
        const float* sp = sps + (size_t)(t*B + b)*8*200 + tid;
        float s8 = 0.f;
        #pragma unroll
        for (int k = 0; k < 8; ++k) s8 += sp[k*200];
        sc_v = s8;
      }
      if (tid < 256) aux[tid] = sc_v;
      __syncthreads();
      if (tid < 64){
        float m = -1e30f;
        #pragma unroll
        for (int i = 0; i < 4; ++i) m = fmaxf(m, aux[tid + i*64]);
        #pragma unroll
        for (int off = 32; off; off >>= 1) m = fmaxf(m, __shfl_xor(m, off));
        if (tid == 0) smx = m;
      }
      __syncthreads();
      float al = (tid < P) ? __expf(sc_v - smx) : 0.f;
      if (tid < 256) aux[tid] = al;
      __syncthreads();
      if (tid < 64){
        float s = 0.f;
        #pragma unroll
        for (int i = 0; i < 4; ++i) s += aux[tid + i*64];
        #pragma unroll
        for (int off = 32; off; off >>= 1) s += __shfl_xor(s, off);
        if (tid == 0) sinv = 1.0f/s;
      }
      __syncthreads();
      float a = 0.f;
      for (int p = wv; p < P; p += 8)
        a += aux[p] * feats[((size_t)b*P + p)*512 + sub*64 + l];
      partA[wv][l] = a;
      __syncthreads();
      if (tid < 64){
        float s = 0.f;
        #pragma unroll
        for (int k = 0; k < 8; ++k) s += partA[k][tid];
        cohstore(xcat + (size_t)(t*B + b)*1536 + 512 + sub*64 + tid, s * sinv);
      }
    }
    bar_grid(fg1, gd1, gen);

    // ---- D: gates for 8 cols x 32 batches; 2col x 4batch register tiles ----
    {
      float a0[4], a1[4];
      #pragma unroll
      for (int u = 0; u < 4; ++u){ a0[u] = 0.f; a1[u] = 0.f; }
      const float4* w0 = (const float4*)&Wl[cp*2][k0];
      const float4* w1 = (const float4*)&Wl[cp*2 + 1][k0];
      const float* xb0 = xin + (size_t)(bq*4)*1536 + k0;
      #pragma unroll 6
      for (int i = 0; i < 24; ++i){
        const float4 wa = w0[i], wb = w1[i];
        #pragma unroll
        for (int u = 0; u < 4; ++u){
          const float4 xv = *(const float4*)(xb0 + (size_t)u*1536 + i*4);
          a0[u] += dot4(wa, xv);
          a1[u] += dot4(wb, xv);
        }
      }
      #pragma unroll
      for (int u = 0; u < 4; ++u)
        *(float2*)&red[kseg*264 + (bq*4 + u)*8 + cp*2] = make_float2(a0[u], a1[u]);
    }
    __syncthreads();
    if (tid < 64){
      const int bb = tid >> 1, jj = tid & 1;
      float gv[4];
      #pragma unroll
      for (int g = 0; g < 4; ++g){
        const int c = g*2 + jj;
        float s = bias8[c];
        #pragma unroll
        for (int k = 0; k < 16; ++k) s += red[k*264 + bb*8 + c];
        gv[g] = s;
      }
      const float i_ = sigmoidf_(gv[0]);
      const float f_ = sigmoidf_(gv[1]);
      const float g_ = fast_tanh(gv[2]);
      const float o_ = sigmoidf_(gv[3]);
      const int j = jb + jj;
      const float c_new = f_*c_reg + i_*g_;
      const float h_new = o_*fast_tanh(c_new);
      c_reg = c_new;
      cohstore(xout + (size_t)bb*1536 + 1024 + j, h_new);
      const unsigned short hh = f_to_bf16(h_new);
      hall_h[((size_t)bb*T + t)*512 + j] = hh;
      hall_l[((size_t)bb*T + t)*512 + j] = f_to_bf16(h_new - bf16_to_f(hh));
    }
    bar_grid(fg2, gd2, gen);
  }
}

// ---------------------------------------------------------------------------
extern "C" void kernel_launch(void* const* d_in, const int* in_sizes, int n_in,
                              void* d_out, int out_size, void* d_ws, size_t ws_size,
                              hipStream_t stream)
{
  (void)in_sizes; (void)n_in; (void)out_size;
  const float* features = (const float*)d_in[0];
  const int*   captions = (const int*)d_in[1];
  const float* embed_W  = (const float*)d_in[2];
  const float* attn_W   = (const float*)d_in[3];
  const float* attn_b   = (const float*)d_in[4];
  const float* v_w      = (const float*)d_in[5];
  const float* W_ih     = (const float*)d_in[6];
  const float* W_hh     = (const float*)d_in[7];
  const float* b_ih     = (const float*)d_in[8];
  const float* b_hh     = (const float*)d_in[9];
  const float* lin_W    = (const float*)d_in[10];
  const float* lin_b    = (const float*)d_in[11];
  const float* inith_W  = (const float*)d_in[12];
  const float* inith_b  = (const float*)d_in[13];
  const float* initc_W  = (const float*)d_in[14];
  const float* initc_b  = (const float*)d_in[15];

  // "early" scratch in d_out (dead before final logits GEMM writes d_out)
  char* o = (char*)d_out;
  unsigned short* feat_bf   = (unsigned short*)o; o += (size_t)(B*P)*E*2;   // 6.4MB
  unsigned short* Wf_bf     = (unsigned short*)o; o += (size_t)H*E*2;       // 0.5MB
  float*          feat_proj = (float*)o;          o += (size_t)(B*P)*H*4;   // 12.9MB

  // persistent scratch in d_ws
  const size_t SZ_LIN  = (size_t)V*H*2;               // 32.77MB
  const size_t SZ_HALL = (size_t)(B*T)*H*2;           // 1MB
  const size_t SZ_XCAT = (size_t)(T+1)*B*1536*4;      // 6.49MB
  const size_t SZ_SPS  = (size_t)T*B*8*200*4;         // 6.55MB
  const size_t SZ_ST   = (size_t)B*H*4;               // 64KB
  const size_t SZ_WHT  = (size_t)H*H*4;               // 1MB
  const size_t SZ_FLG  = 4096;
  const size_t need_wo = SZ_LIN + 2*SZ_HALL + SZ_XCAT + SZ_SPS + SZ_ST + SZ_WHT + SZ_FLG;
  const bool three = (ws_size >= need_wo + SZ_LIN);

  char* w = (char*)d_ws;
  unsigned short* lin_hi  = (unsigned short*)w; w += SZ_LIN;
  unsigned short* lin_lo  = (unsigned short*)w; if (three) w += SZ_LIN;
  unsigned short* hall_hi = (unsigned short*)w; w += SZ_HALL;
  unsigned short* hall_lo = (unsigned short*)w; w += SZ_HALL;
  float*          xcat    = (float*)w;          w += SZ_XCAT;
  float*          sps     = (float*)w;          w += SZ_SPS;
  float*          c_state = (float*)w;          w += SZ_ST;
  float*          WhT_ws  = (float*)w;          w += SZ_WHT;
  unsigned*       flags   = (unsigned*)w;       w += SZ_FLG;
  unsigned* fm  = flags;           // [256] mini-barrier flags [b*8+sub]
  unsigned* fg1 = flags + 256;     // [256] grid barrier 1 arrival flags
  unsigned* fg2 = flags + 512;     // [256] grid barrier 2 arrival flags
  unsigned* gd1 = flags + 768;     // [1]   grid barrier 1 done word
  unsigned* gd2 = flags + 768 + 32;// [1]   grid barrier 2 done word

  // --- conversions / gathers / init ---
  split_kernel<<<2048, 256, 0, stream>>>(features, E, 0, B*P, feat_bf, nullptr, E, 0);
  split_kernel<<<256, 256, 0, stream>>>(attn_W, E+H, 0, H, Wf_bf, nullptr, E, 0);
  split_kernel<<<2048, 256, 0, stream>>>(lin_W, 512, 0, V, lin_hi, three ? lin_lo : nullptr, 512, 0);
  embed_kernel<<<B*T, 128, 0, stream>>>(captions, embed_W, xcat);
  prep_kernel<<<B, 512, 0, stream>>>(features, inith_W, inith_b, initc_W, initc_b,
                                     xcat, c_state);
  transpose_wh_kernel<<<64, 256, 0, stream>>>(attn_W, WhT_ws);
  hipMemsetAsync(flags, 0, SZ_FLG, stream);

  // feat_proj = features @ Wf^T (bf16 1-pass; error damped through tanh/softmax)
  gemm_bt_kernel<<<(B*P/128)*(E/128), 256, 0, stream>>>(
      feat_bf, feat_bf, feat_bf, Wf_bf, Wf_bf, Wf_bf,
      feat_proj, nullptr, E, E, 1, B*P/128, 0);

  // --- the whole recurrence in one persistent kernel ---
  loop_kernel<<<NB, NT, 0, stream>>>(
      features, feat_proj, WhT_ws, attn_b, v_w, W_ih, W_hh, b_ih, b_hh,
      xcat, c_state, sps, hall_hi, hall_lo, fm, fg1, fg2, gd1, gd2);

  // --- logits = h_all @ lin_W^T + lin_b (bf16x3, XCD-swizzled grid) ---
  gemm_bt_kernel<<<(V/128)*(B*T/128), 256, 0, stream>>>(
      hall_hi, hall_lo, hall_hi, lin_hi, lin_hi, three ? lin_lo : lin_hi,
      (float*)d_out, lin_b, V, H, three ? 3 : 2, B*T/128, 1);
}